// Round 28
// baseline (2086.166 us; speedup 1.0000x reference)
//
#include <hip/hip_runtime.h>
#include <hip/hip_bf16.h>
#include <math.h>

#define BB 16
#define NN 1024
#define KK 20

// ---------------------------------------------------------------------------
// LAPACK ssyevd (n=3) faithful port, FLOAT32 (references run f32 ssyevd).
// ---------------------------------------------------------------------------

__device__ inline float s_sign(float a, float b) { return b >= 0.0f ? fabsf(a) : -fabsf(a); }

__device__ inline float s_lapy2(float x, float y) {
    float xa = fabsf(x), ya = fabsf(y);
    float w = fmaxf(xa, ya), z = fminf(xa, ya);
    if (z == 0.0f) return w;
    float t = z / w;
    return w * sqrtf(1.0f + t * t);
}

// LAPACK >= 3.10 slartg (new style; c >= 0 always), f32 constants
__device__ inline void s_lartg(float f, float g, float& c, float& s, float& r) {
    const float safmin = 1.1754943508222875e-38f;
    const float safmax = 1.0f / 1.1754943508222875e-38f;
    const float rtmin = 1.0842021724855044e-19f;
    const float rtmax = 9.2233720368547758e+18f;
    float f1 = fabsf(f), g1 = fabsf(g);
    if (g == 0.0f) { c = 1.0f; s = 0.0f; r = f; }
    else if (f == 0.0f) { c = 0.0f; s = (g >= 0.0f ? 1.0f : -1.0f); r = g1; }
    else {
        float d;
        if (f1 > rtmin && f1 < rtmax && g1 > rtmin && g1 < rtmax) {
            d = sqrtf(f * f + g * g);
            c = f1 / d;
            r = (f >= 0.0f ? d : -d);
        } else {
            float u = fminf(safmax, fmaxf(safmin, fmaxf(f1, g1)));
            float fs = f / u, gs = g / u;
            d = sqrtf(fs * fs + gs * gs);
            c = fabsf(fs) / d;
            r = (f >= 0.0f ? d : -d);
            r = r * u;
        }
        s = g / r;
    }
}

__device__ void s_laev2(float a, float b, float cc, float& rt1, float& rt2,
                        float& cs1, float& sn1) {
    float sm = a + cc;
    float df = a - cc;
    float adf = fabsf(df);
    float tb = b + b;
    float ab = fabsf(tb);
    float acmx, acmn;
    if (fabsf(a) > fabsf(cc)) { acmx = a; acmn = cc; } else { acmx = cc; acmn = a; }
    float rt;
    if (adf > ab) { float t = ab / adf; rt = adf * sqrtf(1.0f + t * t); }
    else if (adf < ab) { float t = adf / ab; rt = ab * sqrtf(1.0f + t * t); }
    else rt = ab * sqrtf(2.0f);
    int sgn1;
    if (sm < 0.0f) { rt1 = 0.5f * (sm - rt); sgn1 = -1; rt2 = (acmx / rt1) * acmn - (b / rt1) * b; }
    else if (sm > 0.0f) { rt1 = 0.5f * (sm + rt); sgn1 = 1; rt2 = (acmx / rt1) * acmn - (b / rt1) * b; }
    else { rt1 = 0.5f * rt; rt2 = -0.5f * rt; sgn1 = 1; }
    float cs; int sgn2;
    if (df >= 0.0f) { cs = df + rt; sgn2 = 1; } else { cs = df - rt; sgn2 = -1; }
    float acs = fabsf(cs);
    if (acs > ab) {
        float ct = -tb / cs;
        sn1 = 1.0f / sqrtf(1.0f + ct * ct);
        cs1 = ct * sn1;
    } else {
        if (ab == 0.0f) { cs1 = 1.0f; sn1 = 0.0f; }
        else {
            float tn = -cs / tb;
            cs1 = 1.0f / sqrtf(1.0f + tn * tn);
            sn1 = tn * cs1;
        }
    }
    if (sgn1 == sgn2) { float tn = cs1; cs1 = -sn1; sn1 = tn; }
}

// ssteqr('I', n=3). d[1..3], e[1..2] (1-indexed), z[1..3][1..3] preset to I.
__device__ void ssteqr3(float* d, float* e, float z[4][4]) {
    const float EPS = 5.9604644775390625e-08f;
    const float EPS2 = 3.5527136788005009e-15f;
    const float SAFMIN = 1.1754943508222875e-38f;
    const float SAFMAX = 1.0f / 1.1754943508222875e-38f;
    const float SSFMAX = sqrtf(SAFMAX) / 3.0f;
    const float SSFMIN = sqrtf(SAFMIN) / EPS2;
    const int n = 3;
    float cwork[4], swork[4];
    int nmaxit = n * 30, jtot = 0;
    int l1 = 1, nm1 = n - 1;
    int l, lsv, lend, lendsv, m, iscale;
    float anorm = 0.0f, p, g, r, c, s, f, b, rt1, rt2;
    int i, j, mm;
    float tst, sc, temp, ct, st;

L10:
    if (l1 > n) goto L160;
    if (l1 > 1) e[l1 - 1] = 0.0f;
    if (l1 <= nm1) {
        for (m = l1; m <= nm1; ++m) {
            tst = fabsf(e[m]);
            if (tst == 0.0f) goto L30;
            if (tst <= (sqrtf(fabsf(d[m])) * sqrtf(fabsf(d[m + 1]))) * EPS) { e[m] = 0.0f; goto L30; }
        }
    }
    m = n;
L30:
    l = l1; lsv = l; lend = m; lendsv = lend; l1 = m + 1;
    if (lend == l) goto L10;
    anorm = 0.0f;
    for (i = l; i <= lend; ++i) anorm = fmaxf(anorm, fabsf(d[i]));
    for (i = l; i <= lend - 1; ++i) anorm = fmaxf(anorm, fabsf(e[i]));
    iscale = 0;
    if (anorm == 0.0f) goto L10;
    if (anorm > SSFMAX) {
        iscale = 1; sc = SSFMAX / anorm;
        for (i = l; i <= lend; ++i) d[i] *= sc;
        for (i = l; i <= lend - 1; ++i) e[i] *= sc;
    } else if (anorm < SSFMIN) {
        iscale = 2; sc = SSFMIN / anorm;
        for (i = l; i <= lend; ++i) d[i] *= sc;
        for (i = l; i <= lend - 1; ++i) e[i] *= sc;
    }
    if (fabsf(d[lend]) < fabsf(d[l])) { lend = lsv; l = lendsv; }
    if (lend > l) {
L40:
        if (l != lend) {
            for (m = l; m <= lend - 1; ++m) {
                tst = fabsf(e[m]); tst = tst * tst;
                if (tst <= (EPS2 * fabsf(d[m])) * fabsf(d[m + 1]) + SAFMIN) goto L60;
            }
        }
        m = lend;
L60:
        if (m < lend) e[m] = 0.0f;
        p = d[l];
        if (m == l) goto L80;
        if (m == l + 1) {
            s_laev2(d[l], e[l], d[l + 1], rt1, rt2, c, s);
            for (i = 1; i <= n; ++i) {
                temp = z[i][l + 1];
                z[i][l + 1] = c * temp - s * z[i][l];
                z[i][l] = s * temp + c * z[i][l];
            }
            d[l] = rt1; d[l + 1] = rt2; e[l] = 0.0f;
            l += 2;
            if (l <= lend) goto L40;
            goto L140;
        }
        if (jtot == nmaxit) goto L140;
        ++jtot;
        g = (d[l + 1] - p) / (2.0f * e[l]);
        r = s_lapy2(g, 1.0f);
        g = d[m] - p + (e[l] / (g + s_sign(r, g)));
        s = 1.0f; c = 1.0f; p = 0.0f;
        for (i = m - 1; i >= l; --i) {
            f = s * e[i]; b = c * e[i];
            s_lartg(g, f, c, s, r);
            if (i != m - 1) e[i + 1] = r;
            g = d[i + 1] - p;
            r = (d[i] - g) * s + 2.0f * c * b;
            p = s * r;
            d[i + 1] = g + p;
            g = c * r - b;
            cwork[i] = c; swork[i] = -s;
        }
        mm = m - l + 1;
        for (j = mm - 1; j >= 1; --j) {
            ct = cwork[l + j - 1]; st = swork[l + j - 1];
            for (i = 1; i <= n; ++i) {
                temp = z[i][l + j];
                z[i][l + j] = ct * temp - st * z[i][l + j - 1];
                z[i][l + j - 1] = st * temp + ct * z[i][l + j - 1];
            }
        }
        d[l] = d[l] - p;
        e[l] = g;
        goto L40;
L80:
        d[l] = p;
        l = l + 1;
        if (l <= lend) goto L40;
        goto L140;
    } else {
L90:
        if (l != lend) {
            for (m = l; m >= lend + 1; --m) {
                tst = fabsf(e[m - 1]); tst = tst * tst;
                if (tst <= (EPS2 * fabsf(d[m])) * fabsf(d[m - 1]) + SAFMIN) goto L110;
            }
        }
        m = lend;
L110:
    if (m > lend) e[m - 1] = 0.0f;
        p = d[l];
        if (m == l) goto L130;
        if (m == l - 1) {
            s_laev2(d[l - 1], e[l - 1], d[l], rt1, rt2, c, s);
            for (i = 1; i <= n; ++i) {
                temp = z[i][l];
                z[i][l] = c * temp - s * z[i][l - 1];
                z[i][l - 1] = s * temp + c * z[i][l - 1];
            }
            d[l - 1] = rt1; d[l] = rt2; e[l - 1] = 0.0f;
            l -= 2;
            if (l >= lend) goto L90;
            goto L140;
        }
        if (jtot == nmaxit) goto L140;
        ++jtot;
        g = (d[l - 1] - p) / (2.0f * e[l - 1]);
        r = s_lapy2(g, 1.0f);
        g = d[m] - p + (e[l - 1] / (g + s_sign(r, g)));
        s = 1.0f; c = 1.0f; p = 0.0f;
        for (i = m; i <= l - 1; ++i) {
            f = s * e[i]; b = c * e[i];
            s_lartg(g, f, c, s, r);
            if (i != m) e[i - 1] = r;
            g = d[i] - p;
            r = (d[i + 1] - g) * s + 2.0f * c * b;
            p = s * r;
            d[i] = g + p;
            g = c * r - b;
            cwork[i] = c; swork[i] = s;
        }
        mm = l - m + 1;
        for (j = 1; j <= mm - 1; ++j) {
            ct = cwork[m + j - 1]; st = swork[m + j - 1];
            for (i = 1; i <= n; ++i) {
                temp = z[i][m + j];
                z[i][m + j] = ct * temp - st * z[i][m + j - 1];
                z[i][m + j - 1] = st * temp + ct * z[i][m + j - 1];
            }
        }
        d[l] = d[l] - p;
        e[l - 1] = g;
        goto L90;
L130:
        d[l] = p;
        l = l - 1;
        if (l >= lend) goto L90;
        goto L140;
    }
L140:
    if (iscale == 1) {
        sc = anorm / SSFMAX;
        for (i = lsv; i <= lendsv; ++i) d[i] *= sc;
        for (i = lsv; i <= lendsv - 1; ++i) e[i] *= sc;
    } else if (iscale == 2) {
        sc = anorm / SSFMIN;
        for (i = lsv; i <= lendsv; ++i) d[i] *= sc;
        for (i = lsv; i <= lendsv - 1; ++i) e[i] *= sc;
    }
    if (jtot < nmaxit) goto L10;
    return;
L160:
    for (int ii = 2; ii <= n; ++ii) {
        i = ii - 1; int k = i;
        p = d[i];
        for (j = ii; j <= n; ++j) {
            if (d[j] < p) { k = j; p = d[j]; }
        }
        if (k != i) {
            d[k] = d[i]; d[i] = p;
            for (int rr = 1; rr <= n; ++rr) { float t = z[rr][i]; z[rr][i] = z[rr][k]; z[rr][k] = t; }
        }
    }
}

__device__ void eigh3f(const float A[3][3], float vecs[3][3]) {
    float a00 = A[0][0], a10 = A[1][0], a20 = A[2][0];
    float a11 = A[1][1], a21 = A[2][1], a22 = A[2][2];
    float d[4], e[4], tau1, v2 = 0.0f, beta;
    float alpha = a10, xnorm = fabsf(a20);
    if (xnorm == 0.0f) {
        tau1 = 0.0f; beta = alpha;
    } else {
        beta = -s_sign(s_lapy2(alpha, xnorm), alpha);
        tau1 = (beta - alpha) / beta;
        v2 = a20 * (1.0f / (alpha - beta));
    }
    e[1] = beta;
    if (tau1 != 0.0f) {
        float w0 = tau1 * (a11 + a21 * v2);
        float w1 = tau1 * (a21 + a22 * v2);
        float al = -0.5f * tau1 * (w0 + w1 * v2);
        w0 += al; w1 += al * v2;
        a11 = a11 - w0 - w0;
        a21 = a21 - v2 * w0 - w1;
        a22 = a22 - v2 * w1 - w1 * v2;
    }
    e[2] = a21;
    d[1] = a00; d[2] = a11; d[3] = a22;
    float z[4][4];
    for (int i = 1; i <= 3; ++i)
        for (int j = 1; j <= 3; ++j) z[i][j] = (i == j) ? 1.0f : 0.0f;
    ssteqr3(d, e, z);
    if (tau1 != 0.0f) {
        for (int j = 1; j <= 3; ++j) {
            float sum = z[2][j] + v2 * z[3][j];
            z[2][j] -= tau1 * sum;
            z[3][j] -= tau1 * v2 * sum;
        }
    }
    for (int c = 0; c < 3; ++c) {
        vecs[0][c] = z[1][c + 1];
        vecs[1][c] = z[2][c + 1];
        vecs[2][c] = z[3][c + 1];
    }
}

// ---------------------------------------------------------------------------
// Weight repack (pairs):  wp[(pc*R + r)*2 + k] = w[r][2*pc + k]
// ---------------------------------------------------------------------------
__global__ __launch_bounds__(256) void transpose_w2_kernel(const float* __restrict__ w,
                                                           float* __restrict__ wp,
                                                           int R, int C) {
    int i = blockIdx.x * 256 + threadIdx.x;
    if (i < R * C) {
        int r = i / C, c = i % C;
        int pc = c >> 1, k = c & 1;
        wp[((size_t)pc * R + r) * 2 + k] = w[i];
    }
}

// Weight repack (quads): wq[(qc*R + r)*4 + k] = w[r][4*qc + k]
__global__ __launch_bounds__(256) void transpose_w4_kernel(const float* __restrict__ w,
                                                           float* __restrict__ wq,
                                                           int R, int C) {
    int i = blockIdx.x * 256 + threadIdx.x;
    if (i < R * C) {
        int r = i / C, c = i % C;
        int qc = c >> 2, k = c & 3;
        wq[((size_t)qc * R + r) * 4 + k] = w[i];
    }
}

// Plain transpose: wt[c][r] = w[r][c]   (for w5: 1024x512 -> 512x1024)
__global__ __launch_bounds__(256) void transpose_w_kernel(const float* __restrict__ w,
                                                          float* __restrict__ wt,
                                                          int R, int C) {
    int i = blockIdx.x * 256 + threadIdx.x;
    if (i < R * C) {
        int r = i / C, c = i % C;
        wt[(size_t)c * R + r] = w[i];
    }
}

// ---------------------------------------------------------------------------
// Feature transpose f64: xt[B][N][C] -> xtc[B][C][N], tiled 32x32 via LDS.
// ---------------------------------------------------------------------------
template <int C>
__global__ __launch_bounds__(256) void transpose_x_kernel(const double* __restrict__ xt,
                                                          double* __restrict__ xtc) {
    __shared__ double tile[32][33];
    const int ctiles = C / 32, ntiles = NN / 32;
    int id = blockIdx.x;
    int b = id / (ctiles * ntiles);
    int rem = id % (ctiles * ntiles);
    int ct = rem / ntiles, nt = rem % ntiles;
    int c0 = ct * 32, n0 = nt * 32;
    int tc = threadIdx.x & 31, tr = threadIdx.x >> 5;  // 8 row-groups
    for (int rr = tr; rr < 32; rr += 8)
        tile[rr][tc] = xt[((size_t)b * NN + n0 + rr) * C + c0 + tc];
    __syncthreads();
    for (int rr = tr; rr < 32; rr += 8)
        xtc[((size_t)b * C + c0 + rr) * NN + n0 + tc] = tile[tc][rr];
}

// ---------------------------------------------------------------------------
// Stage A: covariance sums (exact chains; x read from global = same values)
// ---------------------------------------------------------------------------
__global__ __launch_bounds__(256) void cov6_kernel(const float* __restrict__ x,
                                                   double* __restrict__ cov6) {
    int bn = blockIdx.x;
    int b = bn >> 10, n = bn & 1023;
    __shared__ double covp[6][4];
    const float* xb = x + (size_t)b * 3 * NN;
    float cx = xb[n], cy = xb[NN + n], cz = xb[2 * NN + n];
    double c00 = 0, c01 = 0, c02 = 0, c11 = 0, c12 = 0, c22 = 0;
    for (int m = threadIdx.x; m < NN; m += 256) {
        double dx = (double)xb[m] - (double)cx;
        double dy = (double)xb[NN + m] - (double)cy;
        double dz = (double)xb[2 * NN + m] - (double)cz;
        c00 += dx * dx; c01 += dx * dy; c02 += dx * dz;
        c11 += dy * dy; c12 += dy * dz; c22 += dz * dz;
    }
    for (int off = 32; off; off >>= 1) {
        c00 += __shfl_down(c00, off); c01 += __shfl_down(c01, off);
        c02 += __shfl_down(c02, off); c11 += __shfl_down(c11, off);
        c12 += __shfl_down(c12, off); c22 += __shfl_down(c22, off);
    }
    int lane = threadIdx.x & 63, wv = threadIdx.x >> 6;
    if (lane == 0) {
        covp[0][wv] = c00; covp[1][wv] = c01; covp[2][wv] = c02;
        covp[3][wv] = c11; covp[4][wv] = c12; covp[5][wv] = c22;
    }
    __syncthreads();
    if (threadIdx.x == 0) {
        double* outp = cov6 + (size_t)bn * 6;
        outp[0] = covp[0][0] + covp[0][1] + covp[0][2] + covp[0][3];
        outp[1] = covp[1][0] + covp[1][1] + covp[1][2] + covp[1][3];
        outp[2] = covp[2][0] + covp[2][1] + covp[2][2] + covp[2][3];
        outp[3] = covp[3][0] + covp[3][1] + covp[3][2] + covp[3][3];
        outp[4] = covp[4][0] + covp[4][1] + covp[4][2] + covp[4][3];
        outp[5] = covp[5][0] + covp[5][1] + covp[5][2] + covp[5][3];
    }
}

// ---------------------------------------------------------------------------
// Stage B: one thread per point runs the f32 eigensolver (fully parallel).
// ---------------------------------------------------------------------------
__global__ __launch_bounds__(256) void eigh_kernel(const double* __restrict__ cov6,
                                                   double* __restrict__ vecsg) {
    int i = blockIdx.x * 256 + threadIdx.x;
    if (i < BB * NN) {
        const double* s = cov6 + (size_t)i * 6;
        double s00 = s[0], s01 = s[1], s02 = s[2], s11 = s[3], s12 = s[4], s22 = s[5];
        float A[3][3];
        A[0][0] = (float)s00; A[0][1] = (float)s01; A[0][2] = (float)s02;
        A[1][0] = (float)s01; A[1][1] = (float)s11; A[1][2] = (float)s12;
        A[2][0] = (float)s02; A[2][1] = (float)s12; A[2][2] = (float)s22;
        float V[3][3];
        eigh3f(A, V);
        double* vp = vecsg + (size_t)i * 9;
        for (int dd = 0; dd < 3; ++dd)
            for (int cc2 = 0; cc2 < 3; ++cc2) vp[dd * 3 + cc2] = (double)V[dd][cc2];
    }
}

// ---------------------------------------------------------------------------
// Stage C v2: 8 points per block, 512 threads / 8 waves.
// ---------------------------------------------------------------------------
__global__ __launch_bounds__(512) void lf_rest_kernel(
    const float* __restrict__ x, const double* __restrict__ vecsg,
    const float* __restrict__ w1, const float* __restrict__ g1, const float* __restrict__ b1,
    float* __restrict__ x1, double* __restrict__ x1t) {
    int b = blockIdx.x >> 7;            // 128 blocks per batch
    int n0 = (blockIdx.x & 127) << 3;   // 8 queries
    int tid = threadIdx.x;
    int wv = tid >> 6, lane = tid & 63;

    __shared__ float xs[3][NN];
    __shared__ double red8[8][512];
    __shared__ double vq[8][9];
    __shared__ float ctrq[8][3];
    __shared__ int sel8[8][KK];
    __shared__ double ysel8[8][3][KK];

    const float* xb = x + (size_t)b * 3 * NN;
    for (int t = tid; t < 3 * NN; t += 512) xs[t >> 10][t & 1023] = xb[t];
    if (tid < 72) vq[tid / 9][tid % 9] = vecsg[((size_t)(b * NN + n0 + tid / 9)) * 9 + tid % 9];
    if (tid < 24) ctrq[tid / 3][tid % 3] = xb[(tid % 3) * NN + n0 + tid / 3];
    __syncthreads();

    double v[16];
    for (int h = 0; h < 2; ++h) {
        int m = h * 512 + tid;
        float xm0 = xs[0][m], xm1 = xs[1][m], xm2 = xs[2][m];
        double racc[8];
#pragma unroll
        for (int q = 0; q < 8; ++q) {
            double dx = (double)xm0 - (double)ctrq[q][0];
            double dy = (double)xm1 - (double)ctrq[q][1];
            double dz = (double)xm2 - (double)ctrq[q][2];
            double y0 = vq[q][0] * dx + vq[q][3] * dy + vq[q][6] * dz;
            double y1 = vq[q][1] * dx + vq[q][4] * dy + vq[q][7] * dz;
            double y2 = vq[q][2] * dx + vq[q][5] * dy + vq[q][8] * dz;
            racc[q] = y0 * y0 + y1 * y1 + y2 * y2;
        }
        if (h == 1) __syncthreads();   // all half-A reads of red8 complete
#pragma unroll
        for (int q = 0; q < 8; ++q) red8[q][tid] = racc[q];
        __syncthreads();
#pragma unroll
        for (int j = 0; j < 8; ++j) v[8 * h + j] = red8[wv][lane + 64 * j];
    }

    for (int it = 0; it < KK; ++it) {
        double bv = v[0]; int bj = 0;
#pragma unroll
        for (int j = 1; j < 16; ++j) {
            if (v[j] > bv) { bv = v[j]; bj = j; }
        }
        int bm = (bj << 6) + lane;
        for (int off2 = 1; off2 < 64; off2 <<= 1) {
            double ov = __shfl_xor(bv, off2);
            int om = __shfl_xor(bm, off2);
            if (ov > bv || (ov == bv && om < bm)) { bv = ov; bm = om; }
        }
        int cj = bm >> 6;
        bool mine = (bm & 63) == lane;
#pragma unroll
        for (int j = 0; j < 16; ++j)
            if (j == cj && mine) v[j] = -1.0;
        if (lane == 0) sel8[wv][it] = bm;
    }
    __syncthreads();

    // ysel per wave (lane < KK), using this wave's query params
    if (lane < KK) {
        int m = sel8[wv][lane];
        double dx = (double)xs[0][m] - (double)ctrq[wv][0];
        double dy = (double)xs[1][m] - (double)ctrq[wv][1];
        double dz = (double)xs[2][m] - (double)ctrq[wv][2];
        ysel8[wv][0][lane] = vq[wv][0] * dx + vq[wv][3] * dy + vq[wv][6] * dz;
        ysel8[wv][1][lane] = vq[wv][1] * dx + vq[wv][4] * dy + vq[wv][7] * dz;
        ysel8[wv][2][lane] = vq[wv][2] * dx + vq[wv][5] * dy + vq[wv][8] * dz;
    }
    __syncthreads();

    // conv1: all 512 threads, q = wave, o = lane
    {
        int o = lane, q = wv, n = n0 + q;
        double wr0 = w1[o * 6 + 0], wr1 = w1[o * 6 + 1], wr2 = w1[o * 6 + 2];
        double wr3 = w1[o * 6 + 3], wr4 = w1[o * 6 + 4], wr5 = w1[o * 6 + 5];
        const double inv = 1.0 / sqrt(1.0 + 1e-5);
        double go = g1[o], bo = b1[o];
        double best = -INFINITY;
        for (int j = 0; j < KK; ++j) {
            double y0 = ysel8[q][0][j], y1 = ysel8[q][1][j], y2 = ysel8[q][2][j];
            double a = wr0 * y0 + wr1 * y1 + wr2 * y2 + wr3 * y0 + wr4 * y1 + wr5 * y2;
            double h = a * inv * go + bo;
            h = h >= 0.0 ? h : 0.2 * h;
            best = fmax(best, h);
        }
        x1[((size_t)b * 64 + o) * NN + n] = (float)best;
        x1t[((size_t)(b * NN + n)) * 64 + o] = best;
    }
}

// ---------------------------------------------------------------------------
// xx from transposed layout (coalesced): xx[b][m] = sum_c xtc[b][c][m]^2
// ---------------------------------------------------------------------------
template <int C>
__global__ __launch_bounds__(256) void xx_kernel(const double* __restrict__ xtc, double* __restrict__ xx) {
    int i = blockIdx.x * 256 + threadIdx.x;
    if (i < BB * NN) {
        int b = i >> 10, m = i & 1023;
        const double* col = xtc + (size_t)b * C * NN + m;
        double s = 0.0;
        for (int c = 0; c < C; ++c) s = fma(col[(size_t)c * NN], col[(size_t)c * NN], s);
        xx[i] = s;
    }
}

// ---------------------------------------------------------------------------
// KNN v4: 8 queries per block (512 threads, 8 waves). Each thread owns
// m = 2*tid, 2*tid+1 -> ONE dwordx4 load per c. c-loop unrolled 8x.
// ctr reads from global at wave-uniform addresses (scalar loads).
// Bit-exact chains; top-k mapping identical.
// ---------------------------------------------------------------------------
template <int C>
__global__ __launch_bounds__(512) void knn_kernel(const double* __restrict__ xt,
                                                  const double* __restrict__ xtc,
                                                  const double* __restrict__ xx,
                                                  int* __restrict__ idx) {
    int b = blockIdx.x >> 7;            // 128 blocks per batch
    int n0 = (blockIdx.x & 127) << 3;   // 8 queries
    __shared__ alignas(16) double pd8[8][NN];   // exactly 64 KB
    int tid = threadIdx.x;

    const double* qbase = xt + (size_t)(b * NN + n0) * C;     // uniform rows
    const double* colb = xtc + (size_t)b * C * NN + 2 * tid;  // this thread's pair

    double acc[8][2];
#pragma unroll
    for (int q = 0; q < 8; ++q) { acc[q][0] = 0.0; acc[q][1] = 0.0; }
#pragma unroll 8
    for (int c = 0; c < C; ++c) {
        double2 rv = *reinterpret_cast<const double2*>(colb + (size_t)c * NN);
        double c0 = qbase[0 * C + c];
        double c1 = qbase[1 * C + c];
        double c2 = qbase[2 * C + c];
        double c3 = qbase[3 * C + c];
        double c4 = qbase[4 * C + c];
        double c5 = qbase[5 * C + c];
        double c6 = qbase[6 * C + c];
        double c7 = qbase[7 * C + c];
        acc[0][0] = fma(c0, rv.x, acc[0][0]); acc[0][1] = fma(c0, rv.y, acc[0][1]);
        acc[1][0] = fma(c1, rv.x, acc[1][0]); acc[1][1] = fma(c1, rv.y, acc[1][1]);
        acc[2][0] = fma(c2, rv.x, acc[2][0]); acc[2][1] = fma(c2, rv.y, acc[2][1]);
        acc[3][0] = fma(c3, rv.x, acc[3][0]); acc[3][1] = fma(c3, rv.y, acc[3][1]);
        acc[4][0] = fma(c4, rv.x, acc[4][0]); acc[4][1] = fma(c4, rv.y, acc[4][1]);
        acc[5][0] = fma(c5, rv.x, acc[5][0]); acc[5][1] = fma(c5, rv.y, acc[5][1]);
        acc[6][0] = fma(c6, rv.x, acc[6][0]); acc[6][1] = fma(c6, rv.y, acc[6][1]);
        acc[7][0] = fma(c7, rv.x, acc[7][0]); acc[7][1] = fma(c7, rv.y, acc[7][1]);
    }

    double xxq[8];
#pragma unroll
    for (int q = 0; q < 8; ++q) xxq[q] = xx[b * NN + n0 + q];   // uniform -> scalar
    {
        double2 xm2 = *reinterpret_cast<const double2*>(&xx[b * NN + 2 * tid]);
#pragma unroll
        for (int q = 0; q < 8; ++q) {
            double2 o2;
            o2.x = (-xxq[q] + 2.0 * acc[q][0]) - xm2.x;
            o2.y = (-xxq[q] + 2.0 * acc[q][1]) - xm2.y;
            *reinterpret_cast<double2*>(&pd8[q][2 * tid]) = o2;
        }
    }
    __syncthreads();

    int wv = tid >> 6, lane = tid & 63;
    double v[16];
#pragma unroll
    for (int j = 0; j < 16; ++j) v[j] = pd8[wv][lane + 64 * j];
    int* out = idx + (size_t)(b * NN + n0 + wv) * KK;
    for (int it = 0; it < KK; ++it) {
        double bv = v[0]; int bj = 0;
#pragma unroll
        for (int j = 1; j < 16; ++j) {
            if (v[j] > bv) { bv = v[j]; bj = j; }
        }
        int bm = (bj << 6) + lane;
        for (int off = 1; off < 64; off <<= 1) {
            double ov = __shfl_xor(bv, off);
            int om = __shfl_xor(bm, off);
            if (ov > bv || (ov == bv && om < bm)) { bv = ov; bm = om; }
        }
        int cj = bm >> 6;
        bool mine = (bm & 63) == lane;
#pragma unroll
        for (int j = 0; j < 16; ++j)
            if (j == cj && mine) v[j] = -INFINITY;
        if (lane == 0) out[it] = bm;
    }
}

// ---------------------------------------------------------------------------
// Graph conv f64 (layers 2,3). W via paired layout wp[pc][o][2].
// ---------------------------------------------------------------------------
template <int CIN, int COUT, int P>
__global__ __launch_bounds__(256) void conv_kernel(
    const double* __restrict__ xint, const int* __restrict__ idx,
    const float* __restrict__ wp, const float* __restrict__ g, const float* __restrict__ bbias,
    float* __restrict__ xout, double* __restrict__ xoutt) {
    const int bpb = NN / P;
    int b = blockIdx.x / bpb;
    int n0 = (blockIdx.x % bpb) * P;
    int tid = threadIdx.x;
    int o = tid % COUT, p = tid / COUT;
    int n = n0 + p;

    __shared__ alignas(16) double ctr[P][CIN];
    __shared__ alignas(16) double dif[P][KK][CIN];
    __shared__ int midx[P][KK];

    const double* qbase = xint + (size_t)(b * NN + n0) * CIN;
    for (int t = tid; t < P * CIN; t += 256) (&ctr[0][0])[t] = qbase[t];
    for (int t = tid; t < P * KK; t += 256)
        (&midx[0][0])[t] = idx[(size_t)(b * NN + n0 + t / KK) * KK + (t % KK)];
    __syncthreads();
    for (int t = tid; t < P * KK * CIN; t += 256) {
        int p2 = t / (KK * CIN);
        int rem = t % (KK * CIN);
        int j = rem / CIN, c = rem % CIN;
        dif[p2][j][c] = xint[(size_t)(b * NN + midx[p2][j]) * CIN + c] - ctr[p2][c];
    }
    __syncthreads();

    const double inv = 1.0 / sqrt(1.0 + 1e-5);
    const float2* wpo = reinterpret_cast<const float2*>(wp) + o;
    double ct2 = 0.0;
#pragma unroll 4
    for (int c2 = 0; c2 < CIN / 2; ++c2) {
        float2 wv = wpo[(size_t)(CIN / 2 + c2) * COUT];
        double2 cv = *reinterpret_cast<const double2*>(&ctr[p][2 * c2]);
        ct2 = fma((double)wv.x, cv.x, ct2);
        ct2 = fma((double)wv.y, cv.y, ct2);
    }
    double acc[KK];
#pragma unroll
    for (int j = 0; j < KK; ++j) acc[j] = 0.0;
    for (int c2 = 0; c2 < CIN / 2; ++c2) {
        float2 wv = wpo[(size_t)c2 * COUT];
        double wx = (double)wv.x, wy = (double)wv.y;
#pragma unroll
        for (int j = 0; j < KK; ++j) {
            double2 dv = *reinterpret_cast<const double2*>(&dif[p][j][2 * c2]);
            acc[j] = fma(wx, dv.x, acc[j]);
            acc[j] = fma(wy, dv.y, acc[j]);
        }
    }
    double go = g[o], bo = bbias[o];
    double best = -INFINITY;
#pragma unroll
    for (int j = 0; j < KK; ++j) {
        double h = (acc[j] + ct2) * inv * go + bo;
        h = h >= 0.0 ? h : 0.2 * h;
        best = fmax(best, h);
    }
    xout[((size_t)b * COUT + o) * NN + n] = (float)best;
    if (xoutt) xoutt[(size_t)(b * NN + n) * COUT + o] = best;
}

// ---------------------------------------------------------------------------
// Layer 4 reformulated: A[n][o] = W1.x[n], B[n][o] = W2.x[n] (f32 GEMM),
// then epilogue max_j lrelu((A[nbr_j] - A[n] + B[n])*inv*g + b).
// AB layout: AB[b][n][0..255] = A, AB[b][n][256..511] = B.
// ---------------------------------------------------------------------------
__global__ __launch_bounds__(256) void gemm_ab4_kernel(
    const double* __restrict__ x3t, const float* __restrict__ wq,
    float* __restrict__ AB) {
    int b = blockIdx.x >> 8;             // 256 blocks per batch, 4 points each
    int n0 = (blockIdx.x & 255) << 2;
    int o = threadIdx.x;
    __shared__ alignas(16) float xr[4][128];
    for (int t = threadIdx.x; t < 4 * 128; t += 256)
        xr[t >> 7][t & 127] = (float)x3t[((size_t)(b * NN + n0 + (t >> 7))) * 128 + (t & 127)];
    __syncthreads();
    const float4* wqc = reinterpret_cast<const float4*>(wq) + o;  // col o, stride 256
    float accA[4], accB[4];
#pragma unroll
    for (int p = 0; p < 4; ++p) { accA[p] = 0.f; accB[p] = 0.f; }
    for (int qc = 0; qc < 32; ++qc) {
        float4 wv = wqc[(size_t)qc * 256];
#pragma unroll
        for (int p = 0; p < 4; ++p) {
            float4 xv = *reinterpret_cast<const float4*>(&xr[p][4 * qc]);
            accA[p] = fmaf(wv.x, xv.x, accA[p]); accA[p] = fmaf(wv.y, xv.y, accA[p]);
            accA[p] = fmaf(wv.z, xv.z, accA[p]); accA[p] = fmaf(wv.w, xv.w, accA[p]);
        }
    }
    for (int qc = 32; qc < 64; ++qc) {
        float4 wv = wqc[(size_t)qc * 256];
#pragma unroll
        for (int p = 0; p < 4; ++p) {
            float4 xv = *reinterpret_cast<const float4*>(&xr[p][4 * (qc - 32)]);
            accB[p] = fmaf(wv.x, xv.x, accB[p]); accB[p] = fmaf(wv.y, xv.y, accB[p]);
            accB[p] = fmaf(wv.z, xv.z, accB[p]); accB[p] = fmaf(wv.w, xv.w, accB[p]);
        }
    }
#pragma unroll
    for (int p = 0; p < 4; ++p) {
        float* row = AB + ((size_t)(b * NN + n0 + p)) * 512;
        row[o] = accA[p];
        row[256 + o] = accB[p];
    }
}

__global__ __launch_bounds__(256) void epi4_kernel(
    const float* __restrict__ AB, const int* __restrict__ idx,
    const float* __restrict__ g, const float* __restrict__ bbias,
    float* __restrict__ x4b) {
    int b = blockIdx.x >> 8;
    int n0 = (blockIdx.x & 255) << 2;
    int o = threadIdx.x;
    __shared__ int midx[4][KK];
    for (int t = threadIdx.x; t < 4 * KK; t += 256)
        midx[t / KK][t % KK] = idx[(size_t)(b * NN + n0 + t / KK) * KK + (t % KK)];
    __syncthreads();
    const float inv = (float)(1.0 / sqrt(1.0 + 1e-5));
    float s = inv * g[o];
    float bo = bbias[o];
#pragma unroll
    for (int p = 0; p < 4; ++p) {
        const float* ABn = AB + ((size_t)(b * NN + n0 + p)) * 512;
        float base = ABn[256 + o] - ABn[o];
        float best = -INFINITY;
        for (int j = 0; j < KK; ++j) {
            float aj = AB[((size_t)(b * NN + midx[p][j])) * 512 + o];
            float h = fmaf(aj + base, s, bo);
            h = h >= 0.f ? h : 0.2f * h;
            best = fmaxf(best, h);
        }
        x4b[((size_t)b * 256 + o) * NN + n0 + p] = best;
    }
}

// ---------------------------------------------------------------------------
// gemm5 v4: 128x128 tile, 8x8 reg tile (split quads, conflict-free).
// STATIC double-buffer: K-loop unrolled by 2 with four separate LDS arrays
// (compile-time addresses -> no VGPR blowup); ONE barrier per K-tile.
// Per-(o,n) k-chain unchanged (bit-exact elements). Epilogue: shfl_xor
// reduction over 16 tx lanes (r26-validated: pmax bit-exact, psum
// ulp-level on continuous mean path).
// ---------------------------------------------------------------------------
__global__ __launch_bounds__(256) void gemm5_kernel(
    const float* __restrict__ x1, const float* __restrict__ x2,
    const float* __restrict__ x3, const float* __restrict__ x4,
    const float* __restrict__ w5t, const float* __restrict__ g5, const float* __restrict__ b5,
    float* __restrict__ pmax, float* __restrict__ psum) {
    int ot = blockIdx.x, nt = blockIdx.y, b = blockIdx.z;
    int o0 = ot * 128, n0 = nt * 128;
    __shared__ alignas(16) float Wt0[16][132];
    __shared__ alignas(16) float Xt0[16][132];
    __shared__ alignas(16) float Wt1[16][132];
    __shared__ alignas(16) float Xt1[16][132];
    float acc[8][8];
#pragma unroll
    for (int i = 0; i < 8; ++i)
#pragma unroll
        for (int j = 0; j < 8; ++j) acc[i][j] = 0.f;
    int tx = threadIdx.x & 15;
    int ty = threadIdx.x >> 4;
    int ka = threadIdx.x >> 5;      // 0..7  (row for r=0; r=1 uses ka+8)
    int qa = threadIdx.x & 31;      // float4 column 0..31

    float4 wreg0, wreg1, xreg0, xreg1;

    // fetch K-tile at base kk2 into registers
#define FETCH_TILE(kk2)                                                                     \
    {                                                                                       \
        wreg0 = *reinterpret_cast<const float4*>(&w5t[(size_t)((kk2) + ka) * 1024 + o0 + 4 * qa]);      \
        wreg1 = *reinterpret_cast<const float4*>(&w5t[(size_t)((kk2) + ka + 8) * 1024 + o0 + 4 * qa]);  \
        _Pragma("unroll")                                                                   \
        for (int r = 0; r < 2; ++r) {                                                       \
            int c = (kk2) + ka + 8 * r;                                                     \
            const float* src; int coff, CC;                                                 \
            if (c < 64) { src = x1; coff = c; CC = 64; }                                    \
            else if (c < 128) { src = x2; coff = c - 64; CC = 64; }                         \
            else if (c < 256) { src = x3; coff = c - 128; CC = 128; }                       \
            else { src = x4; coff = c - 256; CC = 256; }                                    \
            float4 v = *reinterpret_cast<const float4*>(&src[((size_t)b * CC + coff) * NN + n0 + 4 * qa]); \
            if (r == 0) xreg0 = v; else xreg1 = v;                                          \
        }                                                                                   \
    }

#define DUMP_TILE(W, X)                                                  \
    {                                                                    \
        *reinterpret_cast<float4*>(&W[ka][4 * qa]) = wreg0;              \
        *reinterpret_cast<float4*>(&W[ka + 8][4 * qa]) = wreg1;          \
        *reinterpret_cast<float4*>(&X[ka][4 * qa]) = xreg0;              \
        *reinterpret_cast<float4*>(&X[ka + 8][4 * qa]) = xreg1;          \
    }

#define COMPUTE_TILE(W, X)                                                          \
    {                                                                               \
        _Pragma("unroll")                                                           \
        for (int k = 0; k < 16; ++k) {                                              \
            float4 w0 = *reinterpret_cast<const float4*>(&W[k][ty * 4]);            \
            float4 w1 = *reinterpret_cast<const float4*>(&W[k][64 + ty * 4]);       \
            float4 xa = *reinterpret_cast<const float4*>(&X[k][tx * 4]);            \
            float4 xb2 = *reinterpret_cast<const float4*>(&X[k][64 + tx * 4]);      \
            float wv[8] = {w0.x, w0.y, w0.z, w0.w, w1.x, w1.y, w1.z, w1.w};         \
            float xv[8] = {xa.x, xa.y, xa.z, xa.w, xb2.x, xb2.y, xb2.z, xb2.w};     \
            _Pragma("unroll")                                                       \
            for (int i = 0; i < 8; ++i)                                             \
                _Pragma("unroll")                                                   \
                for (int j = 0; j < 8; ++j) acc[i][j] += wv[i] * xv[j];             \
        }                                                                           \
    }

    // prologue: tile 0 -> buf0
    FETCH_TILE(0);
    DUMP_TILE(Wt0, Xt0);
    __syncthreads();

    for (int kk = 0; kk < 512; kk += 32) {
        // phase A: compute buf0 (tile kk); prefetch tile kk+16 -> buf1
        FETCH_TILE(kk + 16);
        COMPUTE_TILE(Wt0, Xt0);
        DUMP_TILE(Wt1, Xt1);
        __syncthreads();
        // phase B: compute buf1 (tile kk+16); prefetch tile kk+32 -> buf0
        bool moreB = (kk + 32) < 512;
        if (moreB) FETCH_TILE(kk + 32);
        COMPUTE_TILE(Wt1, Xt1);
        if (moreB) {
            DUMP_TILE(Wt0, Xt0);
        }
        __syncthreads();
    }
#undef FETCH_TILE
#undef DUMP_TILE
#undef COMPUTE_TILE

    const float inv = (float)(1.0 / sqrt(1.0 + 1e-5));
#pragma unroll
    for (int i = 0; i < 8; ++i) {
        int o = (i < 4) ? (ty * 4 + i) : (64 + ty * 4 + (i - 4));
        float go = g5[o0 + o], bo = b5[o0 + o];
        float mx = -INFINITY, sm = 0.f;
#pragma unroll
        for (int j = 0; j < 8; ++j) {
            float h = acc[i][j] * inv * go + bo;
            h = h >= 0.f ? h : 0.2f * h;
            mx = fmaxf(mx, h);
            sm += h;
        }
        // reduce over the 16 tx lanes (same ty -> same wave, xor stays in group)
#pragma unroll
        for (int off = 1; off < 16; off <<= 1) {
            mx = fmaxf(mx, __shfl_xor(mx, off));
            sm += __shfl_xor(sm, off);
        }
        if (tx == 0) {
            pmax[((size_t)b * 1024 + o0 + o) * 16 + nt] = mx;
            psum[((size_t)b * 1024 + o0 + o) * 16 + nt] = sm;
        }
    }
}

// ---------------------------------------------------------------------------
__global__ __launch_bounds__(256) void poolfc_kernel(
    const float* __restrict__ pmax, const float* __restrict__ psum,
    const float* __restrict__ lw1, const float* __restrict__ g6, const float* __restrict__ b6,
    const float* __restrict__ lw2, const float* __restrict__ lb2,
    const float* __restrict__ g7, const float* __restrict__ b7,
    const float* __restrict__ lw3, const float* __restrict__ lb3,
    float* __restrict__ out) {
    int b = blockIdx.x;
    __shared__ float f[2048];
    __shared__ float f2[512];
    __shared__ float f3[256];
    for (int o = threadIdx.x; o < 1024; o += 256) {
        float mx = -INFINITY, sm = 0.f;
        for (int t = 0; t < 8; ++t) {
            mx = fmaxf(mx, pmax[((size_t)b * 1024 + o) * 16 + t]);
            sm += psum[((size_t)b * 1024 + o) * 16 + t];
        }
        f[o] = mx;
        f[1024 + o] = sm * (1.0f / 1024.0f);
    }
    __syncthreads();
    const float inv = (float)(1.0 / sqrt(1.0 + 1e-5));
    for (int o = threadIdx.x; o < 512; o += 256) {
        const float* wr = lw1 + (size_t)o * 2048;
        float acc = 0.f;
        for (int c = 0; c < 2048; ++c) acc += wr[c] * f[c];
        float h = acc * inv * g6[o] + b6[o];
        f2[o] = h >= 0.f ? h : 0.2f * h;
    }
    __syncthreads();
    for (int o = threadIdx.x; o < 256; o += 256) {
        const float* wr = lw2 + (size_t)o * 512;
        float acc = 0.f;
        for (int c = 0; c < 512; ++c) acc += wr[c] * f2[c];
        acc += lb2[o];
        float h = acc * inv * g7[o] + b7[o];
        f3[o] = h >= 0.f ? h : 0.2f * h;
    }
    __syncthreads();
    if (threadIdx.x < 40) {
        int o = threadIdx.x;
        const float* wr = lw3 + (size_t)o * 256;
        float acc = 0.f;
        for (int c = 0; c < 256; ++c) acc += wr[c] * f3[c];
        out[b * 40 + o] = acc + lb3[o];
    }
}

// ---------------------------------------------------------------------------
extern "C" void kernel_launch(void* const* d_in, const int* in_sizes, int n_in,
                              void* d_out, int out_size, void* d_ws, size_t ws_size,
                              hipStream_t stream) {
    const float* x   = (const float*)d_in[0];
    const float* w1  = (const float*)d_in[1];
    const float* g1  = (const float*)d_in[2];
    const float* b1  = (const float*)d_in[3];
    const float* w2  = (const float*)d_in[4];
    const float* g2  = (const float*)d_in[5];
    const float* b2  = (const float*)d_in[6];
    const float* w3  = (const float*)d_in[7];
    const float* g3  = (const float*)d_in[8];
    const float* b3  = (const float*)d_in[9];
    const float* w4  = (const float*)d_in[10];
    const float* g4  = (const float*)d_in[11];
    const float* b4  = (const float*)d_in[12];
    const float* w5  = (const float*)d_in[13];
    const float* g5  = (const float*)d_in[14];
    const float* b5  = (const float*)d_in[15];
    const float* lw1 = (const float*)d_in[16];
    const float* g6  = (const float*)d_in[17];
    const float* b6  = (const float*)d_in[18];
    const float* lw2 = (const float*)d_in[19];
    const float* lb2 = (const float*)d_in[20];
    const float* g7  = (const float*)d_in[21];
    const float* b7  = (const float*)d_in[22];
    const float* lw3 = (const float*)d_in[23];
    const float* lb3 = (const float*)d_in[24];

    float* ws = (float*)d_ws;
    size_t off = 0;
    float* x1b  = ws + off; off += (size_t)BB * 64 * NN;
    float* x2b  = ws + off; off += (size_t)BB * 64 * NN;
    float* x3b  = ws + off; off += (size_t)BB * 128 * NN;
    float* x4b  = ws + off; off += (size_t)BB * 256 * NN;
    float* pmax = ws + off; off += (size_t)BB * 1024 * 16;
    float* psum = ws + off; off += (size_t)BB * 1024 * 16;
    int*   idxb = (int*)(ws + off); off += (size_t)BB * NN * KK;
    float* w2t  = ws + off; off += (size_t)64 * 128;
    float* w3t  = ws + off; off += (size_t)128 * 128;
    float* w4t  = ws + off; off += (size_t)256 * 256;
    float* w5t  = ws + off; off += (size_t)512 * 1024;
    float* ab4  = ws + off; off += (size_t)BB * NN * 512;
    off = (off + 3) & ~(size_t)3;
    double* x1t = (double*)(ws + off); off += (size_t)BB * NN * 64 * 2;
    double* x2t = (double*)(ws + off); off += (size_t)BB * NN * 64 * 2;
    double* x3t = (double*)(ws + off); off += (size_t)BB * NN * 128 * 2;
    double* x1c = (double*)(ws + off); off += (size_t)BB * 64 * NN * 2;
    double* x2c = (double*)(ws + off); off += (size_t)BB * 64 * NN * 2;
    double* x3c = (double*)(ws + off); off += (size_t)BB * 128 * NN * 2;
    double* xxd = (double*)(ws + off); off += (size_t)BB * NN * 2;
    double* cov6g = (double*)(ws + off); off += (size_t)BB * NN * 6 * 2;
    double* vecsg = (double*)(ws + off); off += (size_t)BB * NN * 9 * 2;

    dim3 blk(256);
    dim3 blk512(512);
    transpose_w2_kernel<<<dim3((64 * 128 + 255) / 256), blk, 0, stream>>>(w2, w2t, 64, 128);
    transpose_w2_kernel<<<dim3((128 * 128 + 255) / 256), blk, 0, stream>>>(w3, w3t, 128, 128);
    transpose_w4_kernel<<<dim3((256 * 256 + 255) / 256), blk, 0, stream>>>(w4, w4t, 256, 256);
    transpose_w_kernel<<<dim3((1024 * 512 + 255) / 256), blk, 0, stream>>>(w5, w5t, 1024, 512);

    // layer 1 split: cov -> eigh (parallel) -> red/topk/conv1 (8 pts/block)
    cov6_kernel<<<dim3(BB * NN), blk, 0, stream>>>(x, cov6g);
    eigh_kernel<<<dim3(BB * NN / 256), blk, 0, stream>>>(cov6g, vecsg);
    lf_rest_kernel<<<dim3(BB * NN / 8), blk512, 0, stream>>>(x, vecsg, w1, g1, b1, x1b, x1t);

    transpose_x_kernel<64><<<dim3(BB * 2 * 32), blk, 0, stream>>>(x1t, x1c);
    xx_kernel<64><<<dim3(BB * NN / 256), blk, 0, stream>>>(x1c, xxd);
    knn_kernel<64><<<dim3(BB * NN / 8), blk512, 0, stream>>>(x1t, x1c, xxd, idxb);
    conv_kernel<64, 64, 4><<<dim3(BB * NN / 4), blk, 0, stream>>>(x1t, idxb, w2t, g2, b2, x2b, x2t);
    transpose_x_kernel<64><<<dim3(BB * 2 * 32), blk, 0, stream>>>(x2t, x2c);
    xx_kernel<64><<<dim3(BB * NN / 256), blk, 0, stream>>>(x2c, xxd);
    knn_kernel<64><<<dim3(BB * NN / 8), blk512, 0, stream>>>(x2t, x2c, xxd, idxb);
    conv_kernel<64, 128, 2><<<dim3(BB * NN / 2), blk, 0, stream>>>(x2t, idxb, w3t, g3, b3, x3b, x3t);
    transpose_x_kernel<128><<<dim3(BB * 4 * 32), blk, 0, stream>>>(x3t, x3c);
    xx_kernel<128><<<dim3(BB * NN / 256), blk, 0, stream>>>(x3c, xxd);
    knn_kernel<128><<<dim3(BB * NN / 8), blk512, 0, stream>>>(x3t, x3c, xxd, idxb);
    // layer 4: GEMM (A,B) + gather-max epilogue
    gemm_ab4_kernel<<<dim3(BB * NN / 4), blk, 0, stream>>>(x3t, w4t, ab4);
    epi4_kernel<<<dim3(BB * NN / 4), blk, 0, stream>>>(ab4, idxb, g4, b4, x4b);
    gemm5_kernel<<<dim3(8, 8, BB), blk, 0, stream>>>(x1b, x2b, x3b, x4b, w5t, g5, b5, pmax, psum);
    poolfc_kernel<<<dim3(BB), blk, 0, stream>>>(pmax, psum, lw1, g6, b6, lw2, lb2, g7, b7, lw3, lb3,
                                                (float*)d_out);
}

// Round 29
// 1492.541 us; speedup vs baseline: 1.3977x; 1.3977x over previous
//
#include <hip/hip_runtime.h>
#include <hip/hip_bf16.h>
#include <math.h>

#define BB 16
#define NN 1024
#define KK 20

// ---------------------------------------------------------------------------
// LAPACK ssyevd (n=3) faithful port, FLOAT32 (references run f32 ssyevd).
// ---------------------------------------------------------------------------

__device__ inline float s_sign(float a, float b) { return b >= 0.0f ? fabsf(a) : -fabsf(a); }

__device__ inline float s_lapy2(float x, float y) {
    float xa = fabsf(x), ya = fabsf(y);
    float w = fmaxf(xa, ya), z = fminf(xa, ya);
    if (z == 0.0f) return w;
    float t = z / w;
    return w * sqrtf(1.0f + t * t);
}

// LAPACK >= 3.10 slartg (new style; c >= 0 always), f32 constants
__device__ inline void s_lartg(float f, float g, float& c, float& s, float& r) {
    const float safmin = 1.1754943508222875e-38f;
    const float safmax = 1.0f / 1.1754943508222875e-38f;
    const float rtmin = 1.0842021724855044e-19f;
    const float rtmax = 9.2233720368547758e+18f;
    float f1 = fabsf(f), g1 = fabsf(g);
    if (g == 0.0f) { c = 1.0f; s = 0.0f; r = f; }
    else if (f == 0.0f) { c = 0.0f; s = (g >= 0.0f ? 1.0f : -1.0f); r = g1; }
    else {
        float d;
        if (f1 > rtmin && f1 < rtmax && g1 > rtmin && g1 < rtmax) {
            d = sqrtf(f * f + g * g);
            c = f1 / d;
            r = (f >= 0.0f ? d : -d);
        } else {
            float u = fminf(safmax, fmaxf(safmin, fmaxf(f1, g1)));
            float fs = f / u, gs = g / u;
            d = sqrtf(fs * fs + gs * gs);
            c = fabsf(fs) / d;
            r = (f >= 0.0f ? d : -d);
            r = r * u;
        }
        s = g / r;
    }
}

__device__ void s_laev2(float a, float b, float cc, float& rt1, float& rt2,
                        float& cs1, float& sn1) {
    float sm = a + cc;
    float df = a - cc;
    float adf = fabsf(df);
    float tb = b + b;
    float ab = fabsf(tb);
    float acmx, acmn;
    if (fabsf(a) > fabsf(cc)) { acmx = a; acmn = cc; } else { acmx = cc; acmn = a; }
    float rt;
    if (adf > ab) { float t = ab / adf; rt = adf * sqrtf(1.0f + t * t); }
    else if (adf < ab) { float t = adf / ab; rt = ab * sqrtf(1.0f + t * t); }
    else rt = ab * sqrtf(2.0f);
    int sgn1;
    if (sm < 0.0f) { rt1 = 0.5f * (sm - rt); sgn1 = -1; rt2 = (acmx / rt1) * acmn - (b / rt1) * b; }
    else if (sm > 0.0f) { rt1 = 0.5f * (sm + rt); sgn1 = 1; rt2 = (acmx / rt1) * acmn - (b / rt1) * b; }
    else { rt1 = 0.5f * rt; rt2 = -0.5f * rt; sgn1 = 1; }
    float cs; int sgn2;
    if (df >= 0.0f) { cs = df + rt; sgn2 = 1; } else { cs = df - rt; sgn2 = -1; }
    float acs = fabsf(cs);
    if (acs > ab) {
        float ct = -tb / cs;
        sn1 = 1.0f / sqrtf(1.0f + ct * ct);
        cs1 = ct * sn1;
    } else {
        if (ab == 0.0f) { cs1 = 1.0f; sn1 = 0.0f; }
        else {
            float tn = -cs / tb;
            cs1 = 1.0f / sqrtf(1.0f + tn * tn);
            sn1 = tn * cs1;
        }
    }
    if (sgn1 == sgn2) { float tn = cs1; cs1 = -sn1; sn1 = tn; }
}

// ssteqr('I', n=3). d[1..3], e[1..2] (1-indexed), z[1..3][1..3] preset to I.
__device__ void ssteqr3(float* d, float* e, float z[4][4]) {
    const float EPS = 5.9604644775390625e-08f;
    const float EPS2 = 3.5527136788005009e-15f;
    const float SAFMIN = 1.1754943508222875e-38f;
    const float SAFMAX = 1.0f / 1.1754943508222875e-38f;
    const float SSFMAX = sqrtf(SAFMAX) / 3.0f;
    const float SSFMIN = sqrtf(SAFMIN) / EPS2;
    const int n = 3;
    float cwork[4], swork[4];
    int nmaxit = n * 30, jtot = 0;
    int l1 = 1, nm1 = n - 1;
    int l, lsv, lend, lendsv, m, iscale;
    float anorm = 0.0f, p, g, r, c, s, f, b, rt1, rt2;
    int i, j, mm;
    float tst, sc, temp, ct, st;

L10:
    if (l1 > n) goto L160;
    if (l1 > 1) e[l1 - 1] = 0.0f;
    if (l1 <= nm1) {
        for (m = l1; m <= nm1; ++m) {
            tst = fabsf(e[m]);
            if (tst == 0.0f) goto L30;
            if (tst <= (sqrtf(fabsf(d[m])) * sqrtf(fabsf(d[m + 1]))) * EPS) { e[m] = 0.0f; goto L30; }
        }
    }
    m = n;
L30:
    l = l1; lsv = l; lend = m; lendsv = lend; l1 = m + 1;
    if (lend == l) goto L10;
    anorm = 0.0f;
    for (i = l; i <= lend; ++i) anorm = fmaxf(anorm, fabsf(d[i]));
    for (i = l; i <= lend - 1; ++i) anorm = fmaxf(anorm, fabsf(e[i]));
    iscale = 0;
    if (anorm == 0.0f) goto L10;
    if (anorm > SSFMAX) {
        iscale = 1; sc = SSFMAX / anorm;
        for (i = l; i <= lend; ++i) d[i] *= sc;
        for (i = l; i <= lend - 1; ++i) e[i] *= sc;
    } else if (anorm < SSFMIN) {
        iscale = 2; sc = SSFMIN / anorm;
        for (i = l; i <= lend; ++i) d[i] *= sc;
        for (i = l; i <= lend - 1; ++i) e[i] *= sc;
    }
    if (fabsf(d[lend]) < fabsf(d[l])) { lend = lsv; l = lendsv; }
    if (lend > l) {
L40:
        if (l != lend) {
            for (m = l; m <= lend - 1; ++m) {
                tst = fabsf(e[m]); tst = tst * tst;
                if (tst <= (EPS2 * fabsf(d[m])) * fabsf(d[m + 1]) + SAFMIN) goto L60;
            }
        }
        m = lend;
L60:
        if (m < lend) e[m] = 0.0f;
        p = d[l];
        if (m == l) goto L80;
        if (m == l + 1) {
            s_laev2(d[l], e[l], d[l + 1], rt1, rt2, c, s);
            for (i = 1; i <= n; ++i) {
                temp = z[i][l + 1];
                z[i][l + 1] = c * temp - s * z[i][l];
                z[i][l] = s * temp + c * z[i][l];
            }
            d[l] = rt1; d[l + 1] = rt2; e[l] = 0.0f;
            l += 2;
            if (l <= lend) goto L40;
            goto L140;
        }
        if (jtot == nmaxit) goto L140;
        ++jtot;
        g = (d[l + 1] - p) / (2.0f * e[l]);
        r = s_lapy2(g, 1.0f);
        g = d[m] - p + (e[l] / (g + s_sign(r, g)));
        s = 1.0f; c = 1.0f; p = 0.0f;
        for (i = m - 1; i >= l; --i) {
            f = s * e[i]; b = c * e[i];
            s_lartg(g, f, c, s, r);
            if (i != m - 1) e[i + 1] = r;
            g = d[i + 1] - p;
            r = (d[i] - g) * s + 2.0f * c * b;
            p = s * r;
            d[i + 1] = g + p;
            g = c * r - b;
            cwork[i] = c; swork[i] = -s;
        }
        mm = m - l + 1;
        for (j = mm - 1; j >= 1; --j) {
            ct = cwork[l + j - 1]; st = swork[l + j - 1];
            for (i = 1; i <= n; ++i) {
                temp = z[i][l + j];
                z[i][l + j] = ct * temp - st * z[i][l + j - 1];
                z[i][l + j - 1] = st * temp + ct * z[i][l + j - 1];
            }
        }
        d[l] = d[l] - p;
        e[l] = g;
        goto L40;
L80:
        d[l] = p;
        l = l + 1;
        if (l <= lend) goto L40;
        goto L140;
    } else {
L90:
        if (l != lend) {
            for (m = l; m >= lend + 1; --m) {
                tst = fabsf(e[m - 1]); tst = tst * tst;
                if (tst <= (EPS2 * fabsf(d[m])) * fabsf(d[m - 1]) + SAFMIN) goto L110;
            }
        }
        m = lend;
L110:
    if (m > lend) e[m - 1] = 0.0f;
        p = d[l];
        if (m == l) goto L130;
        if (m == l - 1) {
            s_laev2(d[l - 1], e[l - 1], d[l], rt1, rt2, c, s);
            for (i = 1; i <= n; ++i) {
                temp = z[i][l];
                z[i][l] = c * temp - s * z[i][l - 1];
                z[i][l - 1] = s * temp + c * z[i][l - 1];
            }
            d[l - 1] = rt1; d[l] = rt2; e[l - 1] = 0.0f;
            l -= 2;
            if (l >= lend) goto L90;
            goto L140;
        }
        if (jtot == nmaxit) goto L140;
        ++jtot;
        g = (d[l - 1] - p) / (2.0f * e[l - 1]);
        r = s_lapy2(g, 1.0f);
        g = d[m] - p + (e[l - 1] / (g + s_sign(r, g)));
        s = 1.0f; c = 1.0f; p = 0.0f;
        for (i = m; i <= l - 1; ++i) {
            f = s * e[i]; b = c * e[i];
            s_lartg(g, f, c, s, r);
            if (i != m) e[i - 1] = r;
            g = d[i] - p;
            r = (d[i + 1] - g) * s + 2.0f * c * b;
            p = s * r;
            d[i] = g + p;
            g = c * r - b;
            cwork[i] = c; swork[i] = s;
        }
        mm = l - m + 1;
        for (j = 1; j <= mm - 1; ++j) {
            ct = cwork[m + j - 1]; st = swork[m + j - 1];
            for (i = 1; i <= n; ++i) {
                temp = z[i][m + j];
                z[i][m + j] = ct * temp - st * z[i][m + j - 1];
                z[i][m + j - 1] = st * temp + ct * z[i][m + j - 1];
            }
        }
        d[l] = d[l] - p;
        e[l - 1] = g;
        goto L90;
L130:
        d[l] = p;
        l = l - 1;
        if (l >= lend) goto L90;
        goto L140;
    }
L140:
    if (iscale == 1) {
        sc = anorm / SSFMAX;
        for (i = lsv; i <= lendsv; ++i) d[i] *= sc;
        for (i = lsv; i <= lendsv - 1; ++i) e[i] *= sc;
    } else if (iscale == 2) {
        sc = anorm / SSFMIN;
        for (i = lsv; i <= lendsv; ++i) d[i] *= sc;
        for (i = lsv; i <= lendsv - 1; ++i) e[i] *= sc;
    }
    if (jtot < nmaxit) goto L10;
    return;
L160:
    for (int ii = 2; ii <= n; ++ii) {
        i = ii - 1; int k = i;
        p = d[i];
        for (j = ii; j <= n; ++j) {
            if (d[j] < p) { k = j; p = d[j]; }
        }
        if (k != i) {
            d[k] = d[i]; d[i] = p;
            for (int rr = 1; rr <= n; ++rr) { float t = z[rr][i]; z[rr][i] = z[rr][k]; z[rr][k] = t; }
        }
    }
}

__device__ void eigh3f(const float A[3][3], float vecs[3][3]) {
    float a00 = A[0][0], a10 = A[1][0], a20 = A[2][0];
    float a11 = A[1][1], a21 = A[2][1], a22 = A[2][2];
    float d[4], e[4], tau1, v2 = 0.0f, beta;
    float alpha = a10, xnorm = fabsf(a20);
    if (xnorm == 0.0f) {
        tau1 = 0.0f; beta = alpha;
    } else {
        beta = -s_sign(s_lapy2(alpha, xnorm), alpha);
        tau1 = (beta - alpha) / beta;
        v2 = a20 * (1.0f / (alpha - beta));
    }
    e[1] = beta;
    if (tau1 != 0.0f) {
        float w0 = tau1 * (a11 + a21 * v2);
        float w1 = tau1 * (a21 + a22 * v2);
        float al = -0.5f * tau1 * (w0 + w1 * v2);
        w0 += al; w1 += al * v2;
        a11 = a11 - w0 - w0;
        a21 = a21 - v2 * w0 - w1;
        a22 = a22 - v2 * w1 - w1 * v2;
    }
    e[2] = a21;
    d[1] = a00; d[2] = a11; d[3] = a22;
    float z[4][4];
    for (int i = 1; i <= 3; ++i)
        for (int j = 1; j <= 3; ++j) z[i][j] = (i == j) ? 1.0f : 0.0f;
    ssteqr3(d, e, z);
    if (tau1 != 0.0f) {
        for (int j = 1; j <= 3; ++j) {
            float sum = z[2][j] + v2 * z[3][j];
            z[2][j] -= tau1 * sum;
            z[3][j] -= tau1 * v2 * sum;
        }
    }
    for (int c = 0; c < 3; ++c) {
        vecs[0][c] = z[1][c + 1];
        vecs[1][c] = z[2][c + 1];
        vecs[2][c] = z[3][c + 1];
    }
}

// ---------------------------------------------------------------------------
// Weight repack (pairs):  wp[(pc*R + r)*2 + k] = w[r][2*pc + k]
// ---------------------------------------------------------------------------
__global__ __launch_bounds__(256) void transpose_w2_kernel(const float* __restrict__ w,
                                                           float* __restrict__ wp,
                                                           int R, int C) {
    int i = blockIdx.x * 256 + threadIdx.x;
    if (i < R * C) {
        int r = i / C, c = i % C;
        int pc = c >> 1, k = c & 1;
        wp[((size_t)pc * R + r) * 2 + k] = w[i];
    }
}

// Weight repack (quads): wq[(qc*R + r)*4 + k] = w[r][4*qc + k]
__global__ __launch_bounds__(256) void transpose_w4_kernel(const float* __restrict__ w,
                                                           float* __restrict__ wq,
                                                           int R, int C) {
    int i = blockIdx.x * 256 + threadIdx.x;
    if (i < R * C) {
        int r = i / C, c = i % C;
        int qc = c >> 2, k = c & 3;
        wq[((size_t)qc * R + r) * 4 + k] = w[i];
    }
}

// Plain transpose: wt[c][r] = w[r][c]   (for w5: 1024x512 -> 512x1024)
__global__ __launch_bounds__(256) void transpose_w_kernel(const float* __restrict__ w,
                                                          float* __restrict__ wt,
                                                          int R, int C) {
    int i = blockIdx.x * 256 + threadIdx.x;
    if (i < R * C) {
        int r = i / C, c = i % C;
        wt[(size_t)c * R + r] = w[i];
    }
}

// ---------------------------------------------------------------------------
// Feature transpose f64: xt[B][N][C] -> xtc[B][C][N], tiled 32x32 via LDS.
// ---------------------------------------------------------------------------
template <int C>
__global__ __launch_bounds__(256) void transpose_x_kernel(const double* __restrict__ xt,
                                                          double* __restrict__ xtc) {
    __shared__ double tile[32][33];
    const int ctiles = C / 32, ntiles = NN / 32;
    int id = blockIdx.x;
    int b = id / (ctiles * ntiles);
    int rem = id % (ctiles * ntiles);
    int ct = rem / ntiles, nt = rem % ntiles;
    int c0 = ct * 32, n0 = nt * 32;
    int tc = threadIdx.x & 31, tr = threadIdx.x >> 5;  // 8 row-groups
    for (int rr = tr; rr < 32; rr += 8)
        tile[rr][tc] = xt[((size_t)b * NN + n0 + rr) * C + c0 + tc];
    __syncthreads();
    for (int rr = tr; rr < 32; rr += 8)
        xtc[((size_t)b * C + c0 + rr) * NN + n0 + tc] = tile[tc][rr];
}

// ---------------------------------------------------------------------------
// Stage A: covariance sums (exact chains; x read from global = same values)
// ---------------------------------------------------------------------------
__global__ __launch_bounds__(256) void cov6_kernel(const float* __restrict__ x,
                                                   double* __restrict__ cov6) {
    int bn = blockIdx.x;
    int b = bn >> 10, n = bn & 1023;
    __shared__ double covp[6][4];
    const float* xb = x + (size_t)b * 3 * NN;
    float cx = xb[n], cy = xb[NN + n], cz = xb[2 * NN + n];
    double c00 = 0, c01 = 0, c02 = 0, c11 = 0, c12 = 0, c22 = 0;
    for (int m = threadIdx.x; m < NN; m += 256) {
        double dx = (double)xb[m] - (double)cx;
        double dy = (double)xb[NN + m] - (double)cy;
        double dz = (double)xb[2 * NN + m] - (double)cz;
        c00 += dx * dx; c01 += dx * dy; c02 += dx * dz;
        c11 += dy * dy; c12 += dy * dz; c22 += dz * dz;
    }
    for (int off = 32; off; off >>= 1) {
        c00 += __shfl_down(c00, off); c01 += __shfl_down(c01, off);
        c02 += __shfl_down(c02, off); c11 += __shfl_down(c11, off);
        c12 += __shfl_down(c12, off); c22 += __shfl_down(c22, off);
    }
    int lane = threadIdx.x & 63, wv = threadIdx.x >> 6;
    if (lane == 0) {
        covp[0][wv] = c00; covp[1][wv] = c01; covp[2][wv] = c02;
        covp[3][wv] = c11; covp[4][wv] = c12; covp[5][wv] = c22;
    }
    __syncthreads();
    if (threadIdx.x == 0) {
        double* outp = cov6 + (size_t)bn * 6;
        outp[0] = covp[0][0] + covp[0][1] + covp[0][2] + covp[0][3];
        outp[1] = covp[1][0] + covp[1][1] + covp[1][2] + covp[1][3];
        outp[2] = covp[2][0] + covp[2][1] + covp[2][2] + covp[2][3];
        outp[3] = covp[3][0] + covp[3][1] + covp[3][2] + covp[3][3];
        outp[4] = covp[4][0] + covp[4][1] + covp[4][2] + covp[4][3];
        outp[5] = covp[5][0] + covp[5][1] + covp[5][2] + covp[5][3];
    }
}

// ---------------------------------------------------------------------------
// Stage B: one thread per point runs the f32 eigensolver (fully parallel).
// ---------------------------------------------------------------------------
__global__ __launch_bounds__(256) void eigh_kernel(const double* __restrict__ cov6,
                                                   double* __restrict__ vecsg) {
    int i = blockIdx.x * 256 + threadIdx.x;
    if (i < BB * NN) {
        const double* s = cov6 + (size_t)i * 6;
        double s00 = s[0], s01 = s[1], s02 = s[2], s11 = s[3], s12 = s[4], s22 = s[5];
        float A[3][3];
        A[0][0] = (float)s00; A[0][1] = (float)s01; A[0][2] = (float)s02;
        A[1][0] = (float)s01; A[1][1] = (float)s11; A[1][2] = (float)s12;
        A[2][0] = (float)s02; A[2][1] = (float)s12; A[2][2] = (float)s22;
        float V[3][3];
        eigh3f(A, V);
        double* vp = vecsg + (size_t)i * 9;
        for (int dd = 0; dd < 3; ++dd)
            for (int cc2 = 0; cc2 < 3; ++cc2) vp[dd * 3 + cc2] = (double)V[dd][cc2];
    }
}

// ---------------------------------------------------------------------------
// Stage C v2: 8 points per block, 512 threads / 8 waves.
// ---------------------------------------------------------------------------
__global__ __launch_bounds__(512) void lf_rest_kernel(
    const float* __restrict__ x, const double* __restrict__ vecsg,
    const float* __restrict__ w1, const float* __restrict__ g1, const float* __restrict__ b1,
    float* __restrict__ x1, double* __restrict__ x1t) {
    int b = blockIdx.x >> 7;            // 128 blocks per batch
    int n0 = (blockIdx.x & 127) << 3;   // 8 queries
    int tid = threadIdx.x;
    int wv = tid >> 6, lane = tid & 63;

    __shared__ float xs[3][NN];
    __shared__ double red8[8][512];
    __shared__ double vq[8][9];
    __shared__ float ctrq[8][3];
    __shared__ int sel8[8][KK];
    __shared__ double ysel8[8][3][KK];

    const float* xb = x + (size_t)b * 3 * NN;
    for (int t = tid; t < 3 * NN; t += 512) xs[t >> 10][t & 1023] = xb[t];
    if (tid < 72) vq[tid / 9][tid % 9] = vecsg[((size_t)(b * NN + n0 + tid / 9)) * 9 + tid % 9];
    if (tid < 24) ctrq[tid / 3][tid % 3] = xb[(tid % 3) * NN + n0 + tid / 3];
    __syncthreads();

    double v[16];
    for (int h = 0; h < 2; ++h) {
        int m = h * 512 + tid;
        float xm0 = xs[0][m], xm1 = xs[1][m], xm2 = xs[2][m];
        double racc[8];
#pragma unroll
        for (int q = 0; q < 8; ++q) {
            double dx = (double)xm0 - (double)ctrq[q][0];
            double dy = (double)xm1 - (double)ctrq[q][1];
            double dz = (double)xm2 - (double)ctrq[q][2];
            double y0 = vq[q][0] * dx + vq[q][3] * dy + vq[q][6] * dz;
            double y1 = vq[q][1] * dx + vq[q][4] * dy + vq[q][7] * dz;
            double y2 = vq[q][2] * dx + vq[q][5] * dy + vq[q][8] * dz;
            racc[q] = y0 * y0 + y1 * y1 + y2 * y2;
        }
        if (h == 1) __syncthreads();   // all half-A reads of red8 complete
#pragma unroll
        for (int q = 0; q < 8; ++q) red8[q][tid] = racc[q];
        __syncthreads();
#pragma unroll
        for (int j = 0; j < 8; ++j) v[8 * h + j] = red8[wv][lane + 64 * j];
    }

    for (int it = 0; it < KK; ++it) {
        double bv = v[0]; int bj = 0;
#pragma unroll
        for (int j = 1; j < 16; ++j) {
            if (v[j] > bv) { bv = v[j]; bj = j; }
        }
        int bm = (bj << 6) + lane;
        for (int off2 = 1; off2 < 64; off2 <<= 1) {
            double ov = __shfl_xor(bv, off2);
            int om = __shfl_xor(bm, off2);
            if (ov > bv || (ov == bv && om < bm)) { bv = ov; bm = om; }
        }
        int cj = bm >> 6;
        bool mine = (bm & 63) == lane;
#pragma unroll
        for (int j = 0; j < 16; ++j)
            if (j == cj && mine) v[j] = -1.0;
        if (lane == 0) sel8[wv][it] = bm;
    }
    __syncthreads();

    // ysel per wave (lane < KK), using this wave's query params
    if (lane < KK) {
        int m = sel8[wv][lane];
        double dx = (double)xs[0][m] - (double)ctrq[wv][0];
        double dy = (double)xs[1][m] - (double)ctrq[wv][1];
        double dz = (double)xs[2][m] - (double)ctrq[wv][2];
        ysel8[wv][0][lane] = vq[wv][0] * dx + vq[wv][3] * dy + vq[wv][6] * dz;
        ysel8[wv][1][lane] = vq[wv][1] * dx + vq[wv][4] * dy + vq[wv][7] * dz;
        ysel8[wv][2][lane] = vq[wv][2] * dx + vq[wv][5] * dy + vq[wv][8] * dz;
    }
    __syncthreads();

    // conv1: all 512 threads, q = wave, o = lane
    {
        int o = lane, q = wv, n = n0 + q;
        double wr0 = w1[o * 6 + 0], wr1 = w1[o * 6 + 1], wr2 = w1[o * 6 + 2];
        double wr3 = w1[o * 6 + 3], wr4 = w1[o * 6 + 4], wr5 = w1[o * 6 + 5];
        const double inv = 1.0 / sqrt(1.0 + 1e-5);
        double go = g1[o], bo = b1[o];
        double best = -INFINITY;
        for (int j = 0; j < KK; ++j) {
            double y0 = ysel8[q][0][j], y1 = ysel8[q][1][j], y2 = ysel8[q][2][j];
            double a = wr0 * y0 + wr1 * y1 + wr2 * y2 + wr3 * y0 + wr4 * y1 + wr5 * y2;
            double h = a * inv * go + bo;
            h = h >= 0.0 ? h : 0.2 * h;
            best = fmax(best, h);
        }
        x1[((size_t)b * 64 + o) * NN + n] = (float)best;
        x1t[((size_t)(b * NN + n)) * 64 + o] = best;
    }
}

// ---------------------------------------------------------------------------
// xx from transposed layout (coalesced): xx[b][m] = sum_c xtc[b][c][m]^2
// ---------------------------------------------------------------------------
template <int C>
__global__ __launch_bounds__(256) void xx_kernel(const double* __restrict__ xtc, double* __restrict__ xx) {
    int i = blockIdx.x * 256 + threadIdx.x;
    if (i < BB * NN) {
        int b = i >> 10, m = i & 1023;
        const double* col = xtc + (size_t)b * C * NN + m;
        double s = 0.0;
        for (int c = 0; c < C; ++c) s = fma(col[(size_t)c * NN], col[(size_t)c * NN], s);
        xx[i] = s;
    }
}

// ---------------------------------------------------------------------------
// KNN v4: 8 queries per block (512 threads, 8 waves). Each thread owns
// m = 2*tid, 2*tid+1 -> ONE dwordx4 load per c. c-loop unrolled 8x.
// ctr reads from global at wave-uniform addresses (scalar loads).
// Bit-exact chains; top-k mapping identical.
// ---------------------------------------------------------------------------
template <int C>
__global__ __launch_bounds__(512) void knn_kernel(const double* __restrict__ xt,
                                                  const double* __restrict__ xtc,
                                                  const double* __restrict__ xx,
                                                  int* __restrict__ idx) {
    int b = blockIdx.x >> 7;            // 128 blocks per batch
    int n0 = (blockIdx.x & 127) << 3;   // 8 queries
    __shared__ alignas(16) double pd8[8][NN];   // exactly 64 KB
    int tid = threadIdx.x;

    const double* qbase = xt + (size_t)(b * NN + n0) * C;     // uniform rows
    const double* colb = xtc + (size_t)b * C * NN + 2 * tid;  // this thread's pair

    double acc[8][2];
#pragma unroll
    for (int q = 0; q < 8; ++q) { acc[q][0] = 0.0; acc[q][1] = 0.0; }
#pragma unroll 8
    for (int c = 0; c < C; ++c) {
        double2 rv = *reinterpret_cast<const double2*>(colb + (size_t)c * NN);
        double c0 = qbase[0 * C + c];
        double c1 = qbase[1 * C + c];
        double c2 = qbase[2 * C + c];
        double c3 = qbase[3 * C + c];
        double c4 = qbase[4 * C + c];
        double c5 = qbase[5 * C + c];
        double c6 = qbase[6 * C + c];
        double c7 = qbase[7 * C + c];
        acc[0][0] = fma(c0, rv.x, acc[0][0]); acc[0][1] = fma(c0, rv.y, acc[0][1]);
        acc[1][0] = fma(c1, rv.x, acc[1][0]); acc[1][1] = fma(c1, rv.y, acc[1][1]);
        acc[2][0] = fma(c2, rv.x, acc[2][0]); acc[2][1] = fma(c2, rv.y, acc[2][1]);
        acc[3][0] = fma(c3, rv.x, acc[3][0]); acc[3][1] = fma(c3, rv.y, acc[3][1]);
        acc[4][0] = fma(c4, rv.x, acc[4][0]); acc[4][1] = fma(c4, rv.y, acc[4][1]);
        acc[5][0] = fma(c5, rv.x, acc[5][0]); acc[5][1] = fma(c5, rv.y, acc[5][1]);
        acc[6][0] = fma(c6, rv.x, acc[6][0]); acc[6][1] = fma(c6, rv.y, acc[6][1]);
        acc[7][0] = fma(c7, rv.x, acc[7][0]); acc[7][1] = fma(c7, rv.y, acc[7][1]);
    }

    double xxq[8];
#pragma unroll
    for (int q = 0; q < 8; ++q) xxq[q] = xx[b * NN + n0 + q];   // uniform -> scalar
    {
        double2 xm2 = *reinterpret_cast<const double2*>(&xx[b * NN + 2 * tid]);
#pragma unroll
        for (int q = 0; q < 8; ++q) {
            double2 o2;
            o2.x = (-xxq[q] + 2.0 * acc[q][0]) - xm2.x;
            o2.y = (-xxq[q] + 2.0 * acc[q][1]) - xm2.y;
            *reinterpret_cast<double2*>(&pd8[q][2 * tid]) = o2;
        }
    }
    __syncthreads();

    int wv = tid >> 6, lane = tid & 63;
    double v[16];
#pragma unroll
    for (int j = 0; j < 16; ++j) v[j] = pd8[wv][lane + 64 * j];
    int* out = idx + (size_t)(b * NN + n0 + wv) * KK;
    for (int it = 0; it < KK; ++it) {
        double bv = v[0]; int bj = 0;
#pragma unroll
        for (int j = 1; j < 16; ++j) {
            if (v[j] > bv) { bv = v[j]; bj = j; }
        }
        int bm = (bj << 6) + lane;
        for (int off = 1; off < 64; off <<= 1) {
            double ov = __shfl_xor(bv, off);
            int om = __shfl_xor(bm, off);
            if (ov > bv || (ov == bv && om < bm)) { bv = ov; bm = om; }
        }
        int cj = bm >> 6;
        bool mine = (bm & 63) == lane;
#pragma unroll
        for (int j = 0; j < 16; ++j)
            if (j == cj && mine) v[j] = -INFINITY;
        if (lane == 0) out[it] = bm;
    }
}

// ---------------------------------------------------------------------------
// Graph conv f64 (layers 2,3). W via paired layout wp[pc][o][2].
// ---------------------------------------------------------------------------
template <int CIN, int COUT, int P>
__global__ __launch_bounds__(256) void conv_kernel(
    const double* __restrict__ xint, const int* __restrict__ idx,
    const float* __restrict__ wp, const float* __restrict__ g, const float* __restrict__ bbias,
    float* __restrict__ xout, double* __restrict__ xoutt) {
    const int bpb = NN / P;
    int b = blockIdx.x / bpb;
    int n0 = (blockIdx.x % bpb) * P;
    int tid = threadIdx.x;
    int o = tid % COUT, p = tid / COUT;
    int n = n0 + p;

    __shared__ alignas(16) double ctr[P][CIN];
    __shared__ alignas(16) double dif[P][KK][CIN];
    __shared__ int midx[P][KK];

    const double* qbase = xint + (size_t)(b * NN + n0) * CIN;
    for (int t = tid; t < P * CIN; t += 256) (&ctr[0][0])[t] = qbase[t];
    for (int t = tid; t < P * KK; t += 256)
        (&midx[0][0])[t] = idx[(size_t)(b * NN + n0 + t / KK) * KK + (t % KK)];
    __syncthreads();
    for (int t = tid; t < P * KK * CIN; t += 256) {
        int p2 = t / (KK * CIN);
        int rem = t % (KK * CIN);
        int j = rem / CIN, c = rem % CIN;
        dif[p2][j][c] = xint[(size_t)(b * NN + midx[p2][j]) * CIN + c] - ctr[p2][c];
    }
    __syncthreads();

    const double inv = 1.0 / sqrt(1.0 + 1e-5);
    const float2* wpo = reinterpret_cast<const float2*>(wp) + o;
    double ct2 = 0.0;
#pragma unroll 4
    for (int c2 = 0; c2 < CIN / 2; ++c2) {
        float2 wv = wpo[(size_t)(CIN / 2 + c2) * COUT];
        double2 cv = *reinterpret_cast<const double2*>(&ctr[p][2 * c2]);
        ct2 = fma((double)wv.x, cv.x, ct2);
        ct2 = fma((double)wv.y, cv.y, ct2);
    }
    double acc[KK];
#pragma unroll
    for (int j = 0; j < KK; ++j) acc[j] = 0.0;
    for (int c2 = 0; c2 < CIN / 2; ++c2) {
        float2 wv = wpo[(size_t)c2 * COUT];
        double wx = (double)wv.x, wy = (double)wv.y;
#pragma unroll
        for (int j = 0; j < KK; ++j) {
            double2 dv = *reinterpret_cast<const double2*>(&dif[p][j][2 * c2]);
            acc[j] = fma(wx, dv.x, acc[j]);
            acc[j] = fma(wy, dv.y, acc[j]);
        }
    }
    double go = g[o], bo = bbias[o];
    double best = -INFINITY;
#pragma unroll
    for (int j = 0; j < KK; ++j) {
        double h = (acc[j] + ct2) * inv * go + bo;
        h = h >= 0.0 ? h : 0.2 * h;
        best = fmax(best, h);
    }
    xout[((size_t)b * COUT + o) * NN + n] = (float)best;
    if (xoutt) xoutt[(size_t)(b * NN + n) * COUT + o] = best;
}

// ---------------------------------------------------------------------------
// Layer 4 reformulated: A[n][o] = W1.x[n], B[n][o] = W2.x[n] (f32 GEMM),
// then epilogue max_j lrelu((A[nbr_j] - A[n] + B[n])*inv*g + b).
// AB layout: AB[b][n][0..255] = A, AB[b][n][256..511] = B.
// ---------------------------------------------------------------------------
__global__ __launch_bounds__(256) void gemm_ab4_kernel(
    const double* __restrict__ x3t, const float* __restrict__ wq,
    float* __restrict__ AB) {
    int b = blockIdx.x >> 8;             // 256 blocks per batch, 4 points each
    int n0 = (blockIdx.x & 255) << 2;
    int o = threadIdx.x;
    __shared__ alignas(16) float xr[4][128];
    for (int t = threadIdx.x; t < 4 * 128; t += 256)
        xr[t >> 7][t & 127] = (float)x3t[((size_t)(b * NN + n0 + (t >> 7))) * 128 + (t & 127)];
    __syncthreads();
    const float4* wqc = reinterpret_cast<const float4*>(wq) + o;  // col o, stride 256
    float accA[4], accB[4];
#pragma unroll
    for (int p = 0; p < 4; ++p) { accA[p] = 0.f; accB[p] = 0.f; }
    for (int qc = 0; qc < 32; ++qc) {
        float4 wv = wqc[(size_t)qc * 256];
#pragma unroll
        for (int p = 0; p < 4; ++p) {
            float4 xv = *reinterpret_cast<const float4*>(&xr[p][4 * qc]);
            accA[p] = fmaf(wv.x, xv.x, accA[p]); accA[p] = fmaf(wv.y, xv.y, accA[p]);
            accA[p] = fmaf(wv.z, xv.z, accA[p]); accA[p] = fmaf(wv.w, xv.w, accA[p]);
        }
    }
    for (int qc = 32; qc < 64; ++qc) {
        float4 wv = wqc[(size_t)qc * 256];
#pragma unroll
        for (int p = 0; p < 4; ++p) {
            float4 xv = *reinterpret_cast<const float4*>(&xr[p][4 * (qc - 32)]);
            accB[p] = fmaf(wv.x, xv.x, accB[p]); accB[p] = fmaf(wv.y, xv.y, accB[p]);
            accB[p] = fmaf(wv.z, xv.z, accB[p]); accB[p] = fmaf(wv.w, xv.w, accB[p]);
        }
    }
#pragma unroll
    for (int p = 0; p < 4; ++p) {
        float* row = AB + ((size_t)(b * NN + n0 + p)) * 512;
        row[o] = accA[p];
        row[256 + o] = accB[p];
    }
}

__global__ __launch_bounds__(256) void epi4_kernel(
    const float* __restrict__ AB, const int* __restrict__ idx,
    const float* __restrict__ g, const float* __restrict__ bbias,
    float* __restrict__ x4b) {
    int b = blockIdx.x >> 8;
    int n0 = (blockIdx.x & 255) << 2;
    int o = threadIdx.x;
    __shared__ int midx[4][KK];
    for (int t = threadIdx.x; t < 4 * KK; t += 256)
        midx[t / KK][t % KK] = idx[(size_t)(b * NN + n0 + t / KK) * KK + (t % KK)];
    __syncthreads();
    const float inv = (float)(1.0 / sqrt(1.0 + 1e-5));
    float s = inv * g[o];
    float bo = bbias[o];
#pragma unroll
    for (int p = 0; p < 4; ++p) {
        const float* ABn = AB + ((size_t)(b * NN + n0 + p)) * 512;
        float base = ABn[256 + o] - ABn[o];
        float best = -INFINITY;
        for (int j = 0; j < KK; ++j) {
            float aj = AB[((size_t)(b * NN + midx[p][j])) * 512 + o];
            float h = fmaf(aj + base, s, bo);
            h = h >= 0.f ? h : 0.2f * h;
            best = fmaxf(best, h);
        }
        x4b[((size_t)b * 256 + o) * NN + n0 + p] = best;
    }
}

// ---------------------------------------------------------------------------
// gemm5 (r25/r27 proven version): 128x128 tile, 8x8 reg tile split as
// 2x(4o) x 2x(4n), 4-float lane stride (conflict-free). Register
// double-buffered staging via float4 prefetch; single LDS buffer, 2 barriers
// per K-tile. 96 VGPR -> good occupancy. Bit-exact per-(o,n) ascending
// k-chain.
// ---------------------------------------------------------------------------
__global__ __launch_bounds__(256) void gemm5_kernel(
    const float* __restrict__ x1, const float* __restrict__ x2,
    const float* __restrict__ x3, const float* __restrict__ x4,
    const float* __restrict__ w5t, const float* __restrict__ g5, const float* __restrict__ b5,
    float* __restrict__ pmax, float* __restrict__ psum) {
    int ot = blockIdx.x, nt = blockIdx.y, b = blockIdx.z;
    int o0 = ot * 128, n0 = nt * 128;
    __shared__ alignas(16) float Wt[16][132];
    __shared__ alignas(16) float Xt[16][132];
    __shared__ float rmax[128][17];
    __shared__ float rsum[128][17];
    float acc[8][8];
#pragma unroll
    for (int i = 0; i < 8; ++i)
#pragma unroll
        for (int j = 0; j < 8; ++j) acc[i][j] = 0.f;
    int tx = threadIdx.x & 15;
    int ty = threadIdx.x >> 4;
    int ka = threadIdx.x >> 5;      // 0..7  (row for r=0; r=1 uses ka+8)
    int qa = threadIdx.x & 31;      // float4 column 0..31

    float4 wreg0, wreg1, xreg0, xreg1;

    // --- prologue: fetch tile 0 ---
    {
        wreg0 = *reinterpret_cast<const float4*>(&w5t[(size_t)(ka)*1024 + o0 + 4 * qa]);
        wreg1 = *reinterpret_cast<const float4*>(&w5t[(size_t)(ka + 8) * 1024 + o0 + 4 * qa]);
#pragma unroll
        for (int r = 0; r < 2; ++r) {
            int c = ka + 8 * r;
            const float* src; int coff, CC;
            if (c < 64) { src = x1; coff = c; CC = 64; }
            else { src = x2; coff = c - 64; CC = 64; }
            float4 v = *reinterpret_cast<const float4*>(&src[((size_t)b * CC + coff) * NN + n0 + 4 * qa]);
            if (r == 0) xreg0 = v; else xreg1 = v;
        }
        *reinterpret_cast<float4*>(&Wt[ka][4 * qa]) = wreg0;
        *reinterpret_cast<float4*>(&Wt[ka + 8][4 * qa]) = wreg1;
        *reinterpret_cast<float4*>(&Xt[ka][4 * qa]) = xreg0;
        *reinterpret_cast<float4*>(&Xt[ka + 8][4 * qa]) = xreg1;
    }
    __syncthreads();

    for (int kk = 0; kk < 512; kk += 16) {
        bool more = (kk + 16) < 512;
        if (more) {
            int kk2 = kk + 16;
            wreg0 = *reinterpret_cast<const float4*>(&w5t[(size_t)(kk2 + ka) * 1024 + o0 + 4 * qa]);
            wreg1 = *reinterpret_cast<const float4*>(&w5t[(size_t)(kk2 + ka + 8) * 1024 + o0 + 4 * qa]);
#pragma unroll
            for (int r = 0; r < 2; ++r) {
                int c = kk2 + ka + 8 * r;
                const float* src; int coff, CC;
                if (c < 64) { src = x1; coff = c; CC = 64; }
                else if (c < 128) { src = x2; coff = c - 64; CC = 64; }
                else if (c < 256) { src = x3; coff = c - 128; CC = 128; }
                else { src = x4; coff = c - 256; CC = 256; }
                float4 v = *reinterpret_cast<const float4*>(&src[((size_t)b * CC + coff) * NN + n0 + 4 * qa]);
                if (r == 0) xreg0 = v; else xreg1 = v;
            }
        }
#pragma unroll
        for (int k = 0; k < 16; ++k) {
            float4 w0 = *reinterpret_cast<const float4*>(&Wt[k][ty * 4]);
            float4 w1 = *reinterpret_cast<const float4*>(&Wt[k][64 + ty * 4]);
            float4 xa = *reinterpret_cast<const float4*>(&Xt[k][tx * 4]);
            float4 xb2 = *reinterpret_cast<const float4*>(&Xt[k][64 + tx * 4]);
            float wv[8] = {w0.x, w0.y, w0.z, w0.w, w1.x, w1.y, w1.z, w1.w};
            float xv[8] = {xa.x, xa.y, xa.z, xa.w, xb2.x, xb2.y, xb2.z, xb2.w};
#pragma unroll
            for (int i = 0; i < 8; ++i)
#pragma unroll
                for (int j = 0; j < 8; ++j) acc[i][j] += wv[i] * xv[j];
        }
        __syncthreads();
        if (more) {
            *reinterpret_cast<float4*>(&Wt[ka][4 * qa]) = wreg0;
            *reinterpret_cast<float4*>(&Wt[ka + 8][4 * qa]) = wreg1;
            *reinterpret_cast<float4*>(&Xt[ka][4 * qa]) = xreg0;
            *reinterpret_cast<float4*>(&Xt[ka + 8][4 * qa]) = xreg1;
            __syncthreads();
        }
    }
    const float inv = (float)(1.0 / sqrt(1.0 + 1e-5));
#pragma unroll
    for (int i = 0; i < 8; ++i) {
        int o = (i < 4) ? (ty * 4 + i) : (64 + ty * 4 + (i - 4));
        float go = g5[o0 + o], bo = b5[o0 + o];
        float mx = -INFINITY, sm = 0.f;
#pragma unroll
        for (int j = 0; j < 8; ++j) {
            float h = acc[i][j] * inv * go + bo;
            h = h >= 0.f ? h : 0.2f * h;
            mx = fmaxf(mx, h);
            sm += h;
        }
        rmax[o][tx] = mx; rsum[o][tx] = sm;
    }
    __syncthreads();
    if (threadIdx.x < 128) {
        int o = threadIdx.x;
        float mx = -INFINITY, sm = 0.f;
        for (int t = 0; t < 16; ++t) { mx = fmaxf(mx, rmax[o][t]); sm += rsum[o][t]; }
        pmax[((size_t)b * 1024 + o0 + o) * 16 + nt] = mx;
        psum[((size_t)b * 1024 + o0 + o) * 16 + nt] = sm;
    }
}

// ---------------------------------------------------------------------------
__global__ __launch_bounds__(256) void poolfc_kernel(
    const float* __restrict__ pmax, const float* __restrict__ psum,
    const float* __restrict__ lw1, const float* __restrict__ g6, const float* __restrict__ b6,
    const float* __restrict__ lw2, const float* __restrict__ lb2,
    const float* __restrict__ g7, const float* __restrict__ b7,
    const float* __restrict__ lw3, const float* __restrict__ lb3,
    float* __restrict__ out) {
    int b = blockIdx.x;
    __shared__ float f[2048];
    __shared__ float f2[512];
    __shared__ float f3[256];
    for (int o = threadIdx.x; o < 1024; o += 256) {
        float mx = -INFINITY, sm = 0.f;
        for (int t = 0; t < 8; ++t) {
            mx = fmaxf(mx, pmax[((size_t)b * 1024 + o) * 16 + t]);
            sm += psum[((size_t)b * 1024 + o) * 16 + t];
        }
        f[o] = mx;
        f[1024 + o] = sm * (1.0f / 1024.0f);
    }
    __syncthreads();
    const float inv = (float)(1.0 / sqrt(1.0 + 1e-5));
    for (int o = threadIdx.x; o < 512; o += 256) {
        const float* wr = lw1 + (size_t)o * 2048;
        float acc = 0.f;
        for (int c = 0; c < 2048; ++c) acc += wr[c] * f[c];
        float h = acc * inv * g6[o] + b6[o];
        f2[o] = h >= 0.f ? h : 0.2f * h;
    }
    __syncthreads();
    for (int o = threadIdx.x; o < 256; o += 256) {
        const float* wr = lw2 + (size_t)o * 512;
        float acc = 0.f;
        for (int c = 0; c < 512; ++c) acc += wr[c] * f2[c];
        acc += lb2[o];
        float h = acc * inv * g7[o] + b7[o];
        f3[o] = h >= 0.f ? h : 0.2f * h;
    }
    __syncthreads();
    if (threadIdx.x < 40) {
        int o = threadIdx.x;
        const float* wr = lw3 + (size_t)o * 256;
        float acc = 0.f;
        for (int c = 0; c < 256; ++c) acc += wr[c] * f3[c];
        out[b * 40 + o] = acc + lb3[o];
    }
}

// ---------------------------------------------------------------------------
extern "C" void kernel_launch(void* const* d_in, const int* in_sizes, int n_in,
                              void* d_out, int out_size, void* d_ws, size_t ws_size,
                              hipStream_t stream) {
    const float* x   = (const float*)d_in[0];
    const float* w1  = (const float*)d_in[1];
    const float* g1  = (const float*)d_in[2];
    const float* b1  = (const float*)d_in[3];
    const float* w2  = (const float*)d_in[4];
    const float* g2  = (const float*)d_in[5];
    const float* b2  = (const float*)d_in[6];
    const float* w3  = (const float*)d_in[7];
    const float* g3  = (const float*)d_in[8];
    const float* b3  = (const float*)d_in[9];
    const float* w4  = (const float*)d_in[10];
    const float* g4  = (const float*)d_in[11];
    const float* b4  = (const float*)d_in[12];
    const float* w5  = (const float*)d_in[13];
    const float* g5  = (const float*)d_in[14];
    const float* b5  = (const float*)d_in[15];
    const float* lw1 = (const float*)d_in[16];
    const float* g6  = (const float*)d_in[17];
    const float* b6  = (const float*)d_in[18];
    const float* lw2 = (const float*)d_in[19];
    const float* lb2 = (const float*)d_in[20];
    const float* g7  = (const float*)d_in[21];
    const float* b7  = (const float*)d_in[22];
    const float* lw3 = (const float*)d_in[23];
    const float* lb3 = (const float*)d_in[24];

    float* ws = (float*)d_ws;
    size_t off = 0;
    float* x1b  = ws + off; off += (size_t)BB * 64 * NN;
    float* x2b  = ws + off; off += (size_t)BB * 64 * NN;
    float* x3b  = ws + off; off += (size_t)BB * 128 * NN;
    float* x4b  = ws + off; off += (size_t)BB * 256 * NN;
    float* pmax = ws + off; off += (size_t)BB * 1024 * 16;
    float* psum = ws + off; off += (size_t)BB * 1024 * 16;
    int*   idxb = (int*)(ws + off); off += (size_t)BB * NN * KK;
    float* w2t  = ws + off; off += (size_t)64 * 128;
    float* w3t  = ws + off; off += (size_t)128 * 128;
    float* w4t  = ws + off; off += (size_t)256 * 256;
    float* w5t  = ws + off; off += (size_t)512 * 1024;
    float* ab4  = ws + off; off += (size_t)BB * NN * 512;
    off = (off + 3) & ~(size_t)3;
    double* x1t = (double*)(ws + off); off += (size_t)BB * NN * 64 * 2;
    double* x2t = (double*)(ws + off); off += (size_t)BB * NN * 64 * 2;
    double* x3t = (double*)(ws + off); off += (size_t)BB * NN * 128 * 2;
    double* x1c = (double*)(ws + off); off += (size_t)BB * 64 * NN * 2;
    double* x2c = (double*)(ws + off); off += (size_t)BB * 64 * NN * 2;
    double* x3c = (double*)(ws + off); off += (size_t)BB * 128 * NN * 2;
    double* xxd = (double*)(ws + off); off += (size_t)BB * NN * 2;
    double* cov6g = (double*)(ws + off); off += (size_t)BB * NN * 6 * 2;
    double* vecsg = (double*)(ws + off); off += (size_t)BB * NN * 9 * 2;

    dim3 blk(256);
    dim3 blk512(512);
    transpose_w2_kernel<<<dim3((64 * 128 + 255) / 256), blk, 0, stream>>>(w2, w2t, 64, 128);
    transpose_w2_kernel<<<dim3((128 * 128 + 255) / 256), blk, 0, stream>>>(w3, w3t, 128, 128);
    transpose_w4_kernel<<<dim3((256 * 256 + 255) / 256), blk, 0, stream>>>(w4, w4t, 256, 256);
    transpose_w_kernel<<<dim3((1024 * 512 + 255) / 256), blk, 0, stream>>>(w5, w5t, 1024, 512);

    // layer 1 split: cov -> eigh (parallel) -> red/topk/conv1 (8 pts/block)
    cov6_kernel<<<dim3(BB * NN), blk, 0, stream>>>(x, cov6g);
    eigh_kernel<<<dim3(BB * NN / 256), blk, 0, stream>>>(cov6g, vecsg);
    lf_rest_kernel<<<dim3(BB * NN / 8), blk512, 0, stream>>>(x, vecsg, w1, g1, b1, x1b, x1t);

    transpose_x_kernel<64><<<dim3(BB * 2 * 32), blk, 0, stream>>>(x1t, x1c);
    xx_kernel<64><<<dim3(BB * NN / 256), blk, 0, stream>>>(x1c, xxd);
    knn_kernel<64><<<dim3(BB * NN / 8), blk512, 0, stream>>>(x1t, x1c, xxd, idxb);
    conv_kernel<64, 64, 4><<<dim3(BB * NN / 4), blk, 0, stream>>>(x1t, idxb, w2t, g2, b2, x2b, x2t);
    transpose_x_kernel<64><<<dim3(BB * 2 * 32), blk, 0, stream>>>(x2t, x2c);
    xx_kernel<64><<<dim3(BB * NN / 256), blk, 0, stream>>>(x2c, xxd);
    knn_kernel<64><<<dim3(BB * NN / 8), blk512, 0, stream>>>(x2t, x2c, xxd, idxb);
    conv_kernel<64, 128, 2><<<dim3(BB * NN / 2), blk, 0, stream>>>(x2t, idxb, w3t, g3, b3, x3b, x3t);
    transpose_x_kernel<128><<<dim3(BB * 4 * 32), blk, 0, stream>>>(x3t, x3c);
    xx_kernel<128><<<dim3(BB * NN / 256), blk, 0, stream>>>(x3c, xxd);
    knn_kernel<128><<<dim3(BB * NN / 8), blk512, 0, stream>>>(x3t, x3c, xxd, idxb);
    // layer 4: GEMM (A,B) + gather-max epilogue
    gemm_ab4_kernel<<<dim3(BB * NN / 4), blk, 0, stream>>>(x3t, w4t, ab4);
    epi4_kernel<<<dim3(BB * NN / 4), blk, 0, stream>>>(ab4, idxb, g4, b4, x4b);
    gemm5_kernel<<<dim3(8, 8, BB), blk, 0, stream>>>(x1b, x2b, x3b, x4b, w5t, g5, b5, pmax, psum);
    poolfc_kernel<<<dim3(BB), blk, 0, stream>>>(pmax, psum, lw1, g6, b6, lw2, lb2, g7, b7, lw3, lb3,
                                                (float*)d_out);
}